// Round 11
// baseline (429.305 us; speedup 1.0000x reference)
//
#include <hip/hip_runtime.h>
#include <hip/hip_fp16.h>
#include <hip/hip_cooperative_groups.h>

namespace cg = cooperative_groups;

#define N_NODES 50000
#define N_EDGES 800000
#define N_GRAPHS 256
#define NCB 196        // coarse buckets = ceil(50000/256), dst>>8
#define CHUNK 3125     // edges per block in coarse passes (256 blocks)
#define GH_LEN (NCB * 256)   // 50176

// ---------------------------------------------------------------------------
// csr_mega: ONE cooperative kernel (256 blocks x 256 thr) doing the whole
// CSR build + prep, with grid.sync() between phases:
//  P0: coarse histogram (dst>>8) + [pad / bounds / wpack] prep work
//  P1: per-bucket totals    P2: exclusive scan of 196 totals (block 0)
//  P3: per-bucket row scan  P4: coarse scatter (block-local runs)
//  P5: per-bucket counting sort -> packed + rowptr
// Replaces 7 dispatches (and their serialization gaps) with 1.
// ---------------------------------------------------------------------------
__global__ __launch_bounds__(256)
void csr_mega(const int* __restrict__ ER, const int* __restrict__ EC,
              const float* __restrict__ EW, const float* __restrict__ X,
              const int* __restrict__ SEG, const float* __restrict__ W1_1,
              const float* __restrict__ W2_1, int* __restrict__ ghist,
              int* __restrict__ bsum, int2* __restrict__ tmp,
              int2* __restrict__ packed, int* __restrict__ rowptr,
              __half* __restrict__ XPh, float* __restrict__ CI,
              int* __restrict__ start, float* __restrict__ WP)
{
    cg::grid_group grid = cg::this_grid();
    __shared__ int smem[768];
    const int t = threadIdx.x;
    const int b = blockIdx.x;

    // ---- P0a: coarse histogram ----
    {
        for (int i = t; i < NCB; i += 256) smem[i] = 0;
        __syncthreads();
        int lo = b * CHUNK, hi = lo + CHUNK;
        for (int e = lo + t; e < hi; e += 256) atomicAdd(&smem[ER[e] >> 8], 1);
        __syncthreads();
        for (int i = t; i < NCB; i += 256) ghist[i * 256 + b] = smem[i];
    }
    // ---- P0b: prep (pad 6250 tiles, bounds 196, wpack 32), looped ----
    for (int tile = b; tile < 6478; tile += 256) {
        if (tile < 6250) {
            int idx = tile * 256 + t;
            int n = idx >> 5;
            int c = idx & 31;
            float v = (c < 30) ? X[n * 30 + c] : 0.f;
            XPh[(size_t)n * 32 + c] = __float2half(v);
            CI[(size_t)n * 64 + 32 + c] = v;
        } else if (tile < 6446) {
            int n = (tile - 6250) * 256 + t;
            if (n < N_NODES) {
                int g = SEG[n];
                int gprev = (n == 0) ? -1 : SEG[n - 1];
                for (int gg = gprev + 1; gg <= g; ++gg) start[gg] = n;
                if (n == N_NODES - 1)
                    for (int gg = g + 1; gg <= N_GRAPHS; ++gg) start[gg] = N_NODES;
            }
        } else {
            int idx = (tile - 6446) * 256 + t;
            if (idx < 64 * 128) {
                int k = idx >> 7, c = idx & 127;
                float w = 0.f;
                if (k < 30) w = W1_1[k * 128 + c];
                else if (k >= 32 && k < 62) w = W2_1[(k - 32) * 128 + c];
                WP[idx] = w;
            }
        }
    }
    grid.sync();

    // ---- P1: per-bucket totals (blocks 0..195) ----
    if (b < NCB) {
        int v = ghist[b * 256 + t];
        #pragma unroll
        for (int off = 32; off; off >>= 1) v += __shfl_down(v, off, 64);
        if ((t & 63) == 0) smem[t >> 6] = v;
        __syncthreads();
        if (t == 0) bsum[b] = smem[0] + smem[1] + smem[2] + smem[3];
    }
    grid.sync();

    // ---- P2: exclusive scan of NCB totals (block 0) ----
    if (b == 0) {
        int v = (t < NCB) ? bsum[t] : 0;
        smem[t] = v;
        __syncthreads();
        for (int off = 1; off < 256; off <<= 1) {
            int u = (t >= off) ? smem[t - off] : 0;
            __syncthreads();
            smem[t] += u;
            __syncthreads();
        }
        if (t < NCB) bsum[t] = smem[t] - v;
    }
    grid.sync();

    // ---- P3: per-bucket row scan (blocks 0..195), in place ----
    if (b < NCB) {
        int i = b * 256 + t;
        int v = ghist[i];
        smem[t] = v;
        __syncthreads();
        for (int off = 1; off < 256; off <<= 1) {
            int u = (t >= off) ? smem[t - off] : 0;
            __syncthreads();
            smem[t] += u;
            __syncthreads();
        }
        ghist[i] = smem[t] - v + bsum[b];
    }
    grid.sync();

    // ---- P4: coarse scatter into per-block contiguous runs ----
    {
        for (int i = t; i < NCB; i += 256) smem[i] = ghist[i * 256 + b];
        __syncthreads();
        int lo = b * CHUNK, hi = lo + CHUNK;
        for (int e = lo + t; e < hi; e += 256) {
            int d = ER[e];
            int pos = atomicAdd(&smem[d >> 8], 1);
            tmp[pos] = make_int2(EC[e] | ((d & 255) << 16), __float_as_int(EW[e]));
        }
    }
    grid.sync();

    // ---- P5: per-bucket counting sort -> packed + rowptr (blocks 0..195) ----
    if (b < NCB) {
        int* hist = smem;
        int* s    = smem + 256;
        int* cur  = smem + 512;
        int base = ghist[b * 256];
        int end  = (b == NCB - 1) ? N_EDGES : ghist[(b + 1) * 256];
        hist[t] = 0;
        __syncthreads();
        for (int j = base + t; j < end; j += 256)
            atomicAdd(&hist[(tmp[j].x >> 16) & 255], 1);
        __syncthreads();
        int v = hist[t];
        s[t] = v;
        __syncthreads();
        for (int off = 1; off < 256; off <<= 1) {
            int u = (t >= off) ? s[t - off] : 0;
            __syncthreads();
            s[t] += u;
            __syncthreads();
        }
        int excl = s[t] - v;
        int n = b * 256 + t;
        if (n < N_NODES) rowptr[n] = base + excl;
        if (b == NCB - 1 && t == 0) rowptr[N_NODES] = N_EDGES;
        cur[t] = base + excl;
        __syncthreads();
        for (int j = base + t; j < end; j += 256) {
            int2 r = tmp[j];
            int pos = atomicAdd(&cur[(r.x >> 16) & 255], 1);
            packed[pos] = make_int2(r.x & 0xFFFF, r.y);
        }
    }
}

// ---------------------------------------------------------------------------
// Dense GEMM (R9/R10 structure): lane = row, wave owns 16 cols, B via scalar
// path (wave-uniform pointers); fp16 epilogue for gathered operands.
// ---------------------------------------------------------------------------
template<int K, int NW, bool RELU>
__device__ __forceinline__ void stage_A(const float* __restrict__ X, float* As,
                                        int m0)
{
    constexpr int KP = K + 4;
    constexpr int T = NW * 64;
    for (int i = threadIdx.x * 4; i < 64 * K; i += T * 4) {
        int row = i / K;
        int col = i % K;
        int gm = m0 + row;
        float4 v = make_float4(0.f, 0.f, 0.f, 0.f);
        if (gm < N_NODES) v = *(const float4*)(X + (size_t)gm * K + col);
        if (RELU) {
            v.x = fmaxf(v.x, 0.f); v.y = fmaxf(v.y, 0.f);
            v.z = fmaxf(v.z, 0.f); v.w = fmaxf(v.w, 0.f);
        }
        *(float4*)(As + row * KP + col) = v;
    }
    __syncthreads();
}

template<int K>
__device__ __forceinline__ void gemm16(const float* arow,
                                       const float* __restrict__ Wcol,
                                       int wstride, float acc[16])
{
    #pragma unroll
    for (int j = 0; j < 16; ++j) acc[j] = 0.f;
    for (int k = 0; k < K; k += 4) {
        float4 a = *(const float4*)(arow + k);
        float av[4] = {a.x, a.y, a.z, a.w};
        #pragma unroll
        for (int kk = 0; kk < 4; ++kk) {
            const float* wr = Wcol + (k + kk) * wstride;   // uniform address
            #pragma unroll
            for (int j = 0; j < 16; ++j)
                acc[j] = fmaf(av[kk], wr[j], acc[j]);
        }
    }
}

__device__ __forceinline__ void store16f(float* orow, const float acc[16],
                                         const float* __restrict__ Bcol)
{
    #pragma unroll
    for (int j4 = 0; j4 < 4; ++j4) {
        float4 v = make_float4(acc[j4*4+0], acc[j4*4+1], acc[j4*4+2], acc[j4*4+3]);
        if (Bcol) {
            float4 b = *(const float4*)(Bcol + j4 * 4);
            v.x += b.x; v.y += b.y; v.z += b.z; v.w += b.w;
        }
        *(float4*)(orow + j4 * 4) = v;
    }
}

__device__ __forceinline__ void store16h(__half* orow, const float acc[16])
{
    __half2 hb[8];
    #pragma unroll
    for (int j = 0; j < 8; ++j)
        hb[j] = __float22half2_rn(make_float2(acc[2*j], acc[2*j+1]));
    *(uint4*)(orow)     = *(uint4*)&hb[0];
    *(uint4*)(orow + 8) = *(uint4*)&hb[4];
}

// Layer 1: CI (N x 64) @ WP (64 x 128) + b -> H1 fp32 (N x 128). 8 waves.
__global__ __launch_bounds__(512)
void dense1_kernel(const float* __restrict__ CI, const float* __restrict__ WP,
                   const float* __restrict__ Bias, float* __restrict__ H1)
{
    __shared__ float As[64 * 68];
    const int m0 = blockIdx.x * 64;
    stage_A<64, 8, false>(CI, As, m0);
    int wid = __builtin_amdgcn_readfirstlane(threadIdx.x >> 6);
    int lane = threadIdx.x & 63;
    float acc[16];
    gemm16<64>(As + lane * 68, WP + wid * 16, 128, acc);
    int gm = m0 + lane;
    if (gm < N_NODES)
        store16f(H1 + (size_t)gm * 128 + wid * 16, acc, Bias + wid * 16);
}

// Layer 2: relu(h1) (N x 128); waves 0-3 -> W1 -> HW1 fp16, 4-7 -> W2 -> AGG fp32+b.
__global__ __launch_bounds__(512)
void dense2_kernel(const float* __restrict__ X, const float* __restrict__ W1,
                   const float* __restrict__ W2, const float* __restrict__ Bias,
                   __half* __restrict__ HW1h, float* __restrict__ AGG)
{
    __shared__ float As[64 * 132];
    const int m0 = blockIdx.x * 64;
    stage_A<128, 8, true>(X, As, m0);
    int wid = __builtin_amdgcn_readfirstlane(threadIdx.x >> 6);
    int lane = threadIdx.x & 63;
    const float* Wc = (wid < 4) ? (W1 + wid * 16) : (W2 + (wid - 4) * 16);
    float acc[16];
    gemm16<128>(As + lane * 132, Wc, 64, acc);
    int gm = m0 + lane;
    if (gm < N_NODES) {
        if (wid < 4)
            store16h(HW1h + (size_t)gm * 64 + wid * 16, acc);
        else
            store16f(AGG + (size_t)gm * 64 + (wid - 4) * 16, acc,
                     Bias + (wid - 4) * 16);
    }
}

// Layer 3: relu(h2) (N x 64); waves 0-1 -> W1 -> HW1 fp16, 2-3 -> W2 -> AGG fp32+b.
__global__ __launch_bounds__(256)
void dense3_kernel(const float* __restrict__ X, const float* __restrict__ W1,
                   const float* __restrict__ W2, const float* __restrict__ Bias,
                   __half* __restrict__ HW1h, float* __restrict__ AGG)
{
    __shared__ float As[64 * 68];
    const int m0 = blockIdx.x * 64;
    stage_A<64, 4, true>(X, As, m0);
    int wid = __builtin_amdgcn_readfirstlane(threadIdx.x >> 6);
    int lane = threadIdx.x & 63;
    const float* Wc = (wid < 2) ? (W1 + wid * 16) : (W2 + (wid - 2) * 16);
    float acc[16];
    gemm16<64>(As + lane * 68, Wc, 32, acc);
    int gm = m0 + lane;
    if (gm < N_NODES) {
        if (wid < 2)
            store16h(HW1h + (size_t)gm * 32 + wid * 16, acc);
        else
            store16f(AGG + (size_t)gm * 32 + (wid - 2) * 16, acc,
                     Bias + (wid - 2) * 16);
    }
}

// ---------------------------------------------------------------------------
// aggx_h: CI[n][0..31] = sum_j w_j * fp16 XPh[src_j][0..31]  (A @ X)
// ---------------------------------------------------------------------------
__global__ __launch_bounds__(256)
void aggx_h(const __half* __restrict__ XPh, const int* __restrict__ rowptr,
            const int2* __restrict__ packed, float* __restrict__ CI)
{
    int tid = threadIdx.x;
    int local = tid >> 2;
    int q = tid & 3;
    int n = blockIdx.x * 64 + local;
    if (n >= N_NODES) return;
    int r0 = rowptr[n], r1 = rowptr[n + 1];
    float4 acc0 = make_float4(0.f, 0.f, 0.f, 0.f);
    float4 acc1 = make_float4(0.f, 0.f, 0.f, 0.f);
    for (int j = r0; j < r1; ++j) {
        int2 r = packed[j];
        float w = __int_as_float(r.y);
        uint4 raw = *(const uint4*)(XPh + (size_t)r.x * 32 + q * 8);
        const __half2* hp = (const __half2*)&raw;
        float2 f0 = __half22float2(hp[0]);
        float2 f1 = __half22float2(hp[1]);
        float2 f2 = __half22float2(hp[2]);
        float2 f3 = __half22float2(hp[3]);
        acc0.x = fmaf(w, f0.x, acc0.x); acc0.y = fmaf(w, f0.y, acc0.y);
        acc0.z = fmaf(w, f1.x, acc0.z); acc0.w = fmaf(w, f1.y, acc0.w);
        acc1.x = fmaf(w, f2.x, acc1.x); acc1.y = fmaf(w, f2.y, acc1.y);
        acc1.z = fmaf(w, f3.x, acc1.z); acc1.w = fmaf(w, f3.y, acc1.w);
    }
    float* op = CI + (size_t)n * 64 + q * 8;
    *(float4*)op = acc0;
    *(float4*)(op + 4) = acc1;
}

// ---------------------------------------------------------------------------
// spmm_h (layers 2,3): fp16 gather rows, fp32 accumulate on top of AGG.
// ---------------------------------------------------------------------------
template<int FOUT>
__global__ __launch_bounds__(256)
void spmm_h(const __half* __restrict__ H, const int* __restrict__ rowptr,
            const int2* __restrict__ packed, float* __restrict__ AGG)
{
    constexpr int T = FOUT / 8;
    int tid = threadIdx.x;
    int local = tid / T;
    int q = tid % T;
    int n = blockIdx.x * (256 / T) + local;
    if (n >= N_NODES) return;
    int r0 = rowptr[n], r1 = rowptr[n + 1];
    float* ap = AGG + (size_t)n * FOUT + q * 8;
    float4 acc0 = *(const float4*)ap;
    float4 acc1 = *(const float4*)(ap + 4);
    for (int j = r0; j < r1; ++j) {
        int2 r = packed[j];
        float w = __int_as_float(r.y);
        uint4 raw = *(const uint4*)(H + (size_t)r.x * FOUT + q * 8);
        const __half2* hp = (const __half2*)&raw;
        float2 f0 = __half22float2(hp[0]);
        float2 f1 = __half22float2(hp[1]);
        float2 f2 = __half22float2(hp[2]);
        float2 f3 = __half22float2(hp[3]);
        acc0.x = fmaf(w, f0.x, acc0.x); acc0.y = fmaf(w, f0.y, acc0.y);
        acc0.z = fmaf(w, f1.x, acc0.z); acc0.w = fmaf(w, f1.y, acc0.w);
        acc1.x = fmaf(w, f2.x, acc1.x); acc1.y = fmaf(w, f2.y, acc1.y);
        acc1.z = fmaf(w, f3.x, acc1.z); acc1.w = fmaf(w, f3.y, acc1.w);
    }
    *(float4*)ap = acc0;
    *(float4*)(ap + 4) = acc1;
}

// ---------------------------------------------------------------------------
// pool + head fused: one block/graph; mean of relu(H) then softmax(p@wd+bd).
// ---------------------------------------------------------------------------
__global__ __launch_bounds__(256)
void pool_kernel(const float* __restrict__ H, const int* __restrict__ start,
                 const float* __restrict__ WD, const float* __restrict__ BD,
                 float* __restrict__ OUT)
{
    __shared__ float red[8][33];
    int g = blockIdx.x;
    int s = start[g], e = start[g + 1];
    int q = threadIdx.x & 31;
    int lane = threadIdx.x >> 5;
    float acc = 0.f;
    for (int n = s + lane; n < e; n += 8)
        acc += fmaxf(H[(size_t)n * 32 + q], 0.f);
    red[lane][q] = acc;
    __syncthreads();
    if (threadIdx.x < 32) {
        float v = 0.f;
        #pragma unroll
        for (int i = 0; i < 8; ++i) v += red[i][q];
        float inv = (e > s) ? 1.0f / (float)(e - s) : 1.0f;
        float p = v * inv;
        float p0 = p * WD[q * 2 + 0];
        float p1 = p * WD[q * 2 + 1];
        #pragma unroll
        for (int off = 16; off; off >>= 1) {
            p0 += __shfl_down(p0, off, 32);
            p1 += __shfl_down(p1, off, 32);
        }
        if (q == 0) {
            float l0 = p0 + BD[0], l1 = p1 + BD[1];
            float m = fmaxf(l0, l1);
            float e0 = expf(l0 - m), e1 = expf(l1 - m);
            float si = 1.0f / (e0 + e1);
            OUT[g * 2 + 0] = e0 * si;
            OUT[g * 2 + 1] = e1 * si;
        }
    }
}

extern "C" void kernel_launch(void* const* d_in, const int* in_sizes, int n_in,
                              void* d_out, int out_size, void* d_ws, size_t ws_size,
                              hipStream_t stream)
{
    const float* x    = (const float*)d_in[0];
    const float* ew   = (const float*)d_in[1];
    const int*   er   = (const int*)d_in[2];
    const int*   ec   = (const int*)d_in[3];
    const int*   seg  = (const int*)d_in[4];
    const float* w1_1 = (const float*)d_in[5];
    const float* w2_1 = (const float*)d_in[6];
    const float* b_1  = (const float*)d_in[7];
    const float* w1_2 = (const float*)d_in[8];
    const float* w2_2 = (const float*)d_in[9];
    const float* b_2  = (const float*)d_in[10];
    const float* w1_3 = (const float*)d_in[11];
    const float* w2_3 = (const float*)d_in[12];
    const float* b_3  = (const float*)d_in[13];
    const float* wd   = (const float*)d_in[14];
    const float* bd   = (const float*)d_in[15];

    float* ws = (float*)d_ws;
    // Phase 1: CI fp32 (0..3.2M), XPh fp16 (3.2M..4.0M), B=h1 fp32 (6.4..12.8M)
    float*  CI   = ws;                         // N x 64 fp32
    __half* XPh  = (__half*)(ws + 3200000);    // N x 32 fp16
    float*  B    = ws + 6400000;               // N x 128 fp32 (h1)
    int2*   tmp  = (int2*)(ws + 6400000);      // E x int2 (CSR build; dead before h1)
    // Phase 2: H2h fp16 at 0 (CI dead), A2=h2 fp32 at 3.2M (XPh dead)
    __half* H2h  = (__half*)ws;                // N x 64 fp16
    float*  A2   = ws + 3200000;               // N x 64 fp32 (h2)
    // Phase 3: H3h fp16 at 6.4M (B dead), B2=h3 fp32 at 8.0M
    __half* H3h  = (__half*)(ws + 6400000);    // N x 32 fp16
    float*  B2   = ws + 8000000;               // N x 32 fp32 (h3)
    int*    IW   = (int*)d_ws;
    int2*   packed = (int2*)(IW + 12800000);   // E x {src, w}
    int*    rowptr = IW + 14400000;            // N+1
    int*    gofs   = IW + 14460000;            // GH_LEN
    int*    bsum   = IW + 14515000;            // NCB
    int*    start  = IW + 14520000;            // G+1
    float*  WP     = ws + 14540000;            // 64 x 128 packed layer-1 weights

    dim3 blk(256);
    const int MB = (N_NODES + 63) / 64;        // 782

    // ---- CSR build + prep: ONE cooperative kernel (7 dispatches -> 1) ----
    {
        void* args[] = { (void*)&er, (void*)&ec, (void*)&ew, (void*)&x,
                         (void*)&seg, (void*)&w1_1, (void*)&w2_1, (void*)&gofs,
                         (void*)&bsum, (void*)&tmp, (void*)&packed,
                         (void*)&rowptr, (void*)&XPh, (void*)&CI,
                         (void*)&start, (void*)&WP };
        hipLaunchCooperativeKernel((void*)csr_mega, dim3(256), blk, args, 0, stream);
    }

    // Layer 1: CI = [A@X | X], h1 = CI @ wpack + b
    aggx_h<<<dim3(MB), blk, 0, stream>>>(XPh, rowptr, packed, CI);
    dense1_kernel<<<dim3(MB), dim3(512), 0, stream>>>(CI, WP, b_1, B);
    // Layer 2: relu(h1)(128) -> 64; HW1 fp16
    dense2_kernel<<<dim3(MB), dim3(512), 0, stream>>>(B, w1_2, w2_2, b_2, H2h, A2);
    spmm_h<64><<<dim3((N_NODES + 31) / 32), blk, 0, stream>>>(H2h, rowptr, packed, A2);
    // Layer 3: relu(h2)(64) -> 32; HW1 fp16
    dense3_kernel<<<dim3(MB), blk, 0, stream>>>(A2, w1_3, w2_3, b_3, H3h, B2);
    spmm_h<32><<<dim3(MB), blk, 0, stream>>>(H3h, rowptr, packed, B2);

    // Pool + head (fused, atomic-free)
    pool_kernel<<<dim3(N_GRAPHS), blk, 0, stream>>>(B2, start, wd, bd, (float*)d_out);
}

// Round 12
// 268.992 us; speedup vs baseline: 1.5960x; 1.5960x over previous
//
#include <hip/hip_runtime.h>
#include <hip/hip_fp16.h>

#define N_NODES 50000
#define N_EDGES 800000
#define N_GRAPHS 256
#define NCB 196        // coarse buckets = ceil(50000/256), dst>>8
#define CHUNK 3125     // edges per block in coarse passes (256 blocks)

// ---------------------------------------------------------------------------
// CSR build, pass 1a: per-block coarse histogram (dst>>8), bucket-major out.
// ---------------------------------------------------------------------------
__global__ __launch_bounds__(256)
void c_hist(const int* __restrict__ ER, int* __restrict__ ghist)
{
    __shared__ int h[NCB];
    int t = threadIdx.x, blk = blockIdx.x;
    for (int i = t; i < NCB; i += 256) h[i] = 0;
    __syncthreads();
    int lo = blk * CHUNK, hi = lo + CHUNK;
    for (int e = lo + t; e < hi; e += 256) atomicAdd(&h[ER[e] >> 8], 1);
    __syncthreads();
    for (int i = t; i < NCB; i += 256) ghist[i * 256 + blk] = h[i];
}

// ---------------------------------------------------------------------------
// scan1: per-bucket (196 blocks) exclusive scan of the 256 per-block counts,
// in place; bucket total -> bsum[b]. (Replaces 3 scan dispatches; consumers
// recompute the 196-entry bucket-offset scan locally.)
// ---------------------------------------------------------------------------
__global__ __launch_bounds__(256)
void scan1(int* __restrict__ ghist, int* __restrict__ bsum)
{
    __shared__ int s[256];
    int t = threadIdx.x, b = blockIdx.x;
    int i = b * 256 + t;
    int v = ghist[i];
    s[t] = v;
    __syncthreads();
    for (int off = 1; off < 256; off <<= 1) {
        int u = (t >= off) ? s[t - off] : 0;
        __syncthreads();
        s[t] += u;
        __syncthreads();
    }
    ghist[i] = s[t] - v;                 // within-bucket exclusive
    if (t == 255) bsum[b] = s[255];      // bucket total
}

// ---------------------------------------------------------------------------
// c_scatter: coarse scatter into per-block contiguous runs. Bucket base
// offsets computed locally (196-entry LDS scan of bsum).
// Record: x = src | ((dst&255)<<16), y = w bits.
// ---------------------------------------------------------------------------
__global__ __launch_bounds__(256)
void c_scatter(const int* __restrict__ ER, const int* __restrict__ EC,
               const float* __restrict__ EW, const int* __restrict__ ghist,
               const int* __restrict__ bsum, int2* __restrict__ tmp)
{
    __shared__ int s[256];
    __shared__ int cur[NCB];
    int t = threadIdx.x, blk = blockIdx.x;
    int v = (t < NCB) ? bsum[t] : 0;
    s[t] = v;
    __syncthreads();
    for (int off = 1; off < 256; off <<= 1) {
        int u = (t >= off) ? s[t - off] : 0;
        __syncthreads();
        s[t] += u;
        __syncthreads();
    }
    if (t < NCB) cur[t] = (s[t] - v) + ghist[t * 256 + blk];
    __syncthreads();
    int lo = blk * CHUNK, hi = lo + CHUNK;
    for (int e = lo + t; e < hi; e += 256) {
        int d = ER[e];
        int pos = atomicAdd(&cur[d >> 8], 1);
        tmp[pos] = make_int2(EC[e] | ((d & 255) << 16), __float_as_int(EW[e]));
    }
}

// ---------------------------------------------------------------------------
// bsort: per-bucket counting sort by dst&255 -> packed (src,w) + rowptr.
// Bucket base via local 196-entry scan of bsum.
// ---------------------------------------------------------------------------
__global__ __launch_bounds__(256)
void bsort(const int2* __restrict__ tmp, const int* __restrict__ bsum,
           int2* __restrict__ packed, int* __restrict__ rowptr)
{
    __shared__ int s[256];
    __shared__ int hist[256];
    __shared__ int cur[256];
    int t = threadIdx.x, b = blockIdx.x;
    int v = (t < NCB) ? bsum[t] : 0;
    s[t] = v;
    __syncthreads();
    for (int off = 1; off < 256; off <<= 1) {
        int u = (t >= off) ? s[t - off] : 0;
        __syncthreads();
        s[t] += u;
        __syncthreads();
    }
    int cntb = bsum[b];
    int base = s[b] - cntb;
    int end  = base + cntb;
    __syncthreads();

    hist[t] = 0;
    __syncthreads();
    for (int j = base + t; j < end; j += 256)
        atomicAdd(&hist[(tmp[j].x >> 16) & 255], 1);
    __syncthreads();
    int hv = hist[t];
    s[t] = hv;
    __syncthreads();
    for (int off = 1; off < 256; off <<= 1) {
        int u = (t >= off) ? s[t - off] : 0;
        __syncthreads();
        s[t] += u;
        __syncthreads();
    }
    int excl = s[t] - hv;
    int n = b * 256 + t;
    if (n < N_NODES) rowptr[n] = base + excl;
    if (b == NCB - 1 && t == 0) rowptr[N_NODES] = N_EDGES;
    cur[t] = base + excl;
    __syncthreads();
    for (int j = base + t; j < end; j += 256) {
        int2 r = tmp[j];
        int pos = atomicAdd(&cur[(r.x >> 16) & 255], 1);
        packed[pos] = make_int2(r.x & 0xFFFF, r.y);
    }
}

// ---------------------------------------------------------------------------
// prep: pad (XPh fp16, 6250 blocks) + bounds (196) + wpack (32), fused.
// ---------------------------------------------------------------------------
__global__ __launch_bounds__(256)
void prep_kernel(const float* __restrict__ X, const int* __restrict__ SEG,
                 const float* __restrict__ W1, const float* __restrict__ W2,
                 __half* __restrict__ XPh, int* __restrict__ start,
                 float* __restrict__ WP)
{
    int bid = blockIdx.x;
    if (bid < 6250) {                       // pad: N*32 threads exactly
        int idx = bid * 256 + threadIdx.x;
        int n = idx >> 5;
        int c = idx & 31;
        float v = (c < 30) ? X[n * 30 + c] : 0.f;
        XPh[(size_t)n * 32 + c] = __float2half(v);
    } else if (bid < 6250 + 196) {          // bounds
        int n = (bid - 6250) * 256 + threadIdx.x;
        if (n >= N_NODES) return;
        int g = SEG[n];
        int gprev = (n == 0) ? -1 : SEG[n - 1];
        for (int gg = gprev + 1; gg <= g; ++gg) start[gg] = n;
        if (n == N_NODES - 1)
            for (int gg = g + 1; gg <= N_GRAPHS; ++gg) start[gg] = N_NODES;
    } else {                                // wpack: 64 x 128
        int idx = (bid - 6446) * 256 + threadIdx.x;
        if (idx >= 64 * 128) return;
        int k = idx >> 7, c = idx & 127;
        float w = 0.f;
        if (k < 30) w = W1[k * 128 + c];
        else if (k >= 32 && k < 62) w = W2[(k - 32) * 128 + c];
        WP[idx] = w;
    }
}

// ---------------------------------------------------------------------------
// Dense GEMM core (R9/R10): lane = row, wave owns 16 cols, B via scalar path.
// ---------------------------------------------------------------------------
template<int K>
__device__ __forceinline__ void gemm16(const float* arow,
                                       const float* __restrict__ Wcol,
                                       int wstride, float acc[16])
{
    #pragma unroll
    for (int j = 0; j < 16; ++j) acc[j] = 0.f;
    for (int k = 0; k < K; k += 4) {
        float4 a = *(const float4*)(arow + k);
        float av[4] = {a.x, a.y, a.z, a.w};
        #pragma unroll
        for (int kk = 0; kk < 4; ++kk) {
            const float* wr = Wcol + (k + kk) * wstride;   // uniform address
            #pragma unroll
            for (int j = 0; j < 16; ++j)
                acc[j] = fmaf(av[kk], wr[j], acc[j]);
        }
    }
}

__device__ __forceinline__ void store16f(float* orow, const float acc[16],
                                         const float* __restrict__ Bcol)
{
    #pragma unroll
    for (int j4 = 0; j4 < 4; ++j4) {
        float4 v = make_float4(acc[j4*4+0], acc[j4*4+1], acc[j4*4+2], acc[j4*4+3]);
        if (Bcol) {
            float4 b = *(const float4*)(Bcol + j4 * 4);
            v.x += b.x; v.y += b.y; v.z += b.z; v.w += b.w;
        }
        *(float4*)(orow + j4 * 4) = v;
    }
}

__device__ __forceinline__ void store16h(__half* orow, const float acc[16])
{
    __half2 hb[8];
    #pragma unroll
    for (int j = 0; j < 8; ++j)
        hb[j] = __float22half2_rn(make_float2(acc[2*j], acc[2*j+1]));
    *(uint4*)(orow)     = *(uint4*)&hb[0];
    *(uint4*)(orow + 8) = *(uint4*)&hb[4];
}

// ---------------------------------------------------------------------------
// Fused layer 1: gather A@X straight into the LDS A-tile (cols 0..31) +
// stage padded X (cols 32..63), then h1 = [A@X | X] @ WP + b. 512 threads.
// Kills the CI global round-trip and one dispatch.
// ---------------------------------------------------------------------------
__global__ __launch_bounds__(512)
void fused1_kernel(const float* __restrict__ X, const __half* __restrict__ XPh,
                   const int* __restrict__ rowptr, const int2* __restrict__ packed,
                   const float* __restrict__ WP, const float* __restrict__ Bias,
                   float* __restrict__ H1)
{
    __shared__ float As[64 * 68];
    const int tid = threadIdx.x;
    const int m0 = blockIdx.x * 64;

    // stage pad half: As[row][32+c] = (c<30)? X[row][c] : 0
    for (int i = tid; i < 64 * 32; i += 512) {
        int row = i >> 5, c = i & 31;
        int gm = m0 + row;
        As[row * 68 + 32 + c] = (gm < N_NODES && c < 30) ? X[gm * 30 + c] : 0.f;
    }
    // gather half: 8 threads/node, 4 features each -> As[row][0..31]
    {
        int local = tid >> 3;
        int q = tid & 7;
        int n = m0 + local;
        float4 acc = make_float4(0.f, 0.f, 0.f, 0.f);
        if (n < N_NODES) {
            int r0 = rowptr[n], r1 = rowptr[n + 1];
            for (int j = r0; j < r1; ++j) {
                int2 r = packed[j];
                float w = __int_as_float(r.y);
                uint2 raw = *(const uint2*)(XPh + (size_t)r.x * 32 + q * 4);
                const __half2* hp = (const __half2*)&raw;
                float2 f0 = __half22float2(hp[0]);
                float2 f1 = __half22float2(hp[1]);
                acc.x = fmaf(w, f0.x, acc.x); acc.y = fmaf(w, f0.y, acc.y);
                acc.z = fmaf(w, f1.x, acc.z); acc.w = fmaf(w, f1.y, acc.w);
            }
        }
        *(float4*)(As + local * 68 + q * 4) = acc;
    }
    __syncthreads();

    int wid = __builtin_amdgcn_readfirstlane(tid >> 6);
    int lane = tid & 63;
    float acc[16];
    gemm16<64>(As + lane * 68, WP + wid * 16, 128, acc);
    int gm = m0 + lane;
    if (gm < N_NODES)
        store16f(H1 + (size_t)gm * 128 + wid * 16, acc, Bias + wid * 16);
}

// Layer 2: relu(h1) (N x 128); waves 0-3 -> W1 -> HW1 fp16, 4-7 -> W2 -> AGG fp32+b.
__global__ __launch_bounds__(512)
void dense2_kernel(const float* __restrict__ X, const float* __restrict__ W1,
                   const float* __restrict__ W2, const float* __restrict__ Bias,
                   __half* __restrict__ HW1h, float* __restrict__ AGG)
{
    __shared__ float As[64 * 132];
    const int m0 = blockIdx.x * 64;
    for (int i = threadIdx.x * 4; i < 64 * 128; i += 512 * 4) {
        int row = i >> 7, col = i & 127;
        int gm = m0 + row;
        float4 v = make_float4(0.f, 0.f, 0.f, 0.f);
        if (gm < N_NODES) v = *(const float4*)(X + (size_t)gm * 128 + col);
        v.x = fmaxf(v.x, 0.f); v.y = fmaxf(v.y, 0.f);
        v.z = fmaxf(v.z, 0.f); v.w = fmaxf(v.w, 0.f);
        *(float4*)(As + row * 132 + col) = v;
    }
    __syncthreads();
    int wid = __builtin_amdgcn_readfirstlane(threadIdx.x >> 6);
    int lane = threadIdx.x & 63;
    const float* Wc = (wid < 4) ? (W1 + wid * 16) : (W2 + (wid - 4) * 16);
    float acc[16];
    gemm16<128>(As + lane * 132, Wc, 64, acc);
    int gm = m0 + lane;
    if (gm < N_NODES) {
        if (wid < 4)
            store16h(HW1h + (size_t)gm * 64 + wid * 16, acc);
        else
            store16f(AGG + (size_t)gm * 64 + (wid - 4) * 16, acc,
                     Bias + (wid - 4) * 16);
    }
}

// Layer 3: relu(h2) (N x 64); waves 0-1 -> W1 -> HW1 fp16, 2-3 -> W2 -> AGG fp32+b.
__global__ __launch_bounds__(256)
void dense3_kernel(const float* __restrict__ X, const float* __restrict__ W1,
                   const float* __restrict__ W2, const float* __restrict__ Bias,
                   __half* __restrict__ HW1h, float* __restrict__ AGG)
{
    __shared__ float As[64 * 68];
    const int m0 = blockIdx.x * 64;
    for (int i = threadIdx.x * 4; i < 64 * 64; i += 256 * 4) {
        int row = i >> 6, col = i & 63;
        int gm = m0 + row;
        float4 v = make_float4(0.f, 0.f, 0.f, 0.f);
        if (gm < N_NODES) v = *(const float4*)(X + (size_t)gm * 64 + col);
        v.x = fmaxf(v.x, 0.f); v.y = fmaxf(v.y, 0.f);
        v.z = fmaxf(v.z, 0.f); v.w = fmaxf(v.w, 0.f);
        *(float4*)(As + row * 68 + col) = v;
    }
    __syncthreads();
    int wid = __builtin_amdgcn_readfirstlane(threadIdx.x >> 6);
    int lane = threadIdx.x & 63;
    const float* Wc = (wid < 2) ? (W1 + wid * 16) : (W2 + (wid - 2) * 16);
    float acc[16];
    gemm16<64>(As + lane * 68, Wc, 32, acc);
    int gm = m0 + lane;
    if (gm < N_NODES) {
        if (wid < 2)
            store16h(HW1h + (size_t)gm * 32 + wid * 16, acc);
        else
            store16f(AGG + (size_t)gm * 32 + (wid - 2) * 16, acc,
                     Bias + (wid - 2) * 16);
    }
}

// ---------------------------------------------------------------------------
// spmm_h (layers 2,3): fp16 gather rows, fp32 accumulate on top of AGG.
// ---------------------------------------------------------------------------
template<int FOUT>
__global__ __launch_bounds__(256)
void spmm_h(const __half* __restrict__ H, const int* __restrict__ rowptr,
            const int2* __restrict__ packed, float* __restrict__ AGG)
{
    constexpr int T = FOUT / 8;
    int tid = threadIdx.x;
    int local = tid / T;
    int q = tid % T;
    int n = blockIdx.x * (256 / T) + local;
    if (n >= N_NODES) return;
    int r0 = rowptr[n], r1 = rowptr[n + 1];
    float* ap = AGG + (size_t)n * FOUT + q * 8;
    float4 acc0 = *(const float4*)ap;
    float4 acc1 = *(const float4*)(ap + 4);
    for (int j = r0; j < r1; ++j) {
        int2 r = packed[j];
        float w = __int_as_float(r.y);
        uint4 raw = *(const uint4*)(H + (size_t)r.x * FOUT + q * 8);
        const __half2* hp = (const __half2*)&raw;
        float2 f0 = __half22float2(hp[0]);
        float2 f1 = __half22float2(hp[1]);
        float2 f2 = __half22float2(hp[2]);
        float2 f3 = __half22float2(hp[3]);
        acc0.x = fmaf(w, f0.x, acc0.x); acc0.y = fmaf(w, f0.y, acc0.y);
        acc0.z = fmaf(w, f1.x, acc0.z); acc0.w = fmaf(w, f1.y, acc0.w);
        acc1.x = fmaf(w, f2.x, acc1.x); acc1.y = fmaf(w, f2.y, acc1.y);
        acc1.z = fmaf(w, f3.x, acc1.z); acc1.w = fmaf(w, f3.y, acc1.w);
    }
    *(float4*)ap = acc0;
    *(float4*)(ap + 4) = acc1;
}

// ---------------------------------------------------------------------------
// pool + head fused: one block/graph; mean of relu(H) then softmax(p@wd+bd).
// ---------------------------------------------------------------------------
__global__ __launch_bounds__(256)
void pool_kernel(const float* __restrict__ H, const int* __restrict__ start,
                 const float* __restrict__ WD, const float* __restrict__ BD,
                 float* __restrict__ OUT)
{
    __shared__ float red[8][33];
    int g = blockIdx.x;
    int s = start[g], e = start[g + 1];
    int q = threadIdx.x & 31;
    int lane = threadIdx.x >> 5;
    float acc = 0.f;
    for (int n = s + lane; n < e; n += 8)
        acc += fmaxf(H[(size_t)n * 32 + q], 0.f);
    red[lane][q] = acc;
    __syncthreads();
    if (threadIdx.x < 32) {
        float v = 0.f;
        #pragma unroll
        for (int i = 0; i < 8; ++i) v += red[i][q];
        float inv = (e > s) ? 1.0f / (float)(e - s) : 1.0f;
        float p = v * inv;
        float p0 = p * WD[q * 2 + 0];
        float p1 = p * WD[q * 2 + 1];
        #pragma unroll
        for (int off = 16; off; off >>= 1) {
            p0 += __shfl_down(p0, off, 32);
            p1 += __shfl_down(p1, off, 32);
        }
        if (q == 0) {
            float l0 = p0 + BD[0], l1 = p1 + BD[1];
            float m = fmaxf(l0, l1);
            float e0 = expf(l0 - m), e1 = expf(l1 - m);
            float si = 1.0f / (e0 + e1);
            OUT[g * 2 + 0] = e0 * si;
            OUT[g * 2 + 1] = e1 * si;
        }
    }
}

extern "C" void kernel_launch(void* const* d_in, const int* in_sizes, int n_in,
                              void* d_out, int out_size, void* d_ws, size_t ws_size,
                              hipStream_t stream)
{
    const float* x    = (const float*)d_in[0];
    const float* ew   = (const float*)d_in[1];
    const int*   er   = (const int*)d_in[2];
    const int*   ec   = (const int*)d_in[3];
    const int*   seg  = (const int*)d_in[4];
    const float* w1_1 = (const float*)d_in[5];
    const float* w2_1 = (const float*)d_in[6];
    const float* b_1  = (const float*)d_in[7];
    const float* w1_2 = (const float*)d_in[8];
    const float* w2_2 = (const float*)d_in[9];
    const float* b_2  = (const float*)d_in[10];
    const float* w1_3 = (const float*)d_in[11];
    const float* w2_3 = (const float*)d_in[12];
    const float* b_3  = (const float*)d_in[13];
    const float* wd   = (const float*)d_in[14];
    const float* bd   = (const float*)d_in[15];

    float* ws = (float*)d_ws;
    // Phase 1: XPh fp16 (3.2M..4.0M), B=h1 fp32 (6.4..12.8M)
    __half* XPh  = (__half*)(ws + 3200000);    // N x 32 fp16
    float*  B    = ws + 6400000;               // N x 128 fp32 (h1)
    int2*   tmp  = (int2*)(ws + 6400000);      // E x int2 (CSR build; dead before h1)
    // Phase 2: H2h fp16 at 0, A2=h2 fp32 at 3.2M (XPh dead after fused1)
    __half* H2h  = (__half*)ws;                // N x 64 fp16
    float*  A2   = ws + 3200000;               // N x 64 fp32 (h2)
    // Phase 3: H3h fp16 at 6.4M (B dead), B2=h3 fp32 at 8.0M
    __half* H3h  = (__half*)(ws + 6400000);    // N x 32 fp16
    float*  B2   = ws + 8000000;               // N x 32 fp32 (h3)
    int*    IW   = (int*)d_ws;
    int2*   packed = (int2*)(IW + 12800000);   // E x {src, w}
    int*    rowptr = IW + 14400000;            // N+1
    int*    ghist  = IW + 14460000;            // NCB*256
    int*    bsum   = IW + 14515000;            // NCB
    int*    start  = IW + 14520000;            // G+1
    float*  WP     = ws + 14540000;            // 64 x 128 packed layer-1 weights

    dim3 blk(256);
    const int MB = (N_NODES + 63) / 64;        // 782

    // ---- CSR build: hist -> scan1 -> scatter -> bucket sort (4 dispatches) ----
    c_hist<<<dim3(256), blk, 0, stream>>>(er, ghist);
    scan1<<<dim3(NCB), blk, 0, stream>>>(ghist, bsum);
    c_scatter<<<dim3(256), blk, 0, stream>>>(er, ec, ew, ghist, bsum, tmp);
    bsort<<<dim3(NCB), blk, 0, stream>>>(tmp, bsum, packed, rowptr);

    // ---- prep: pad (XPh) + bounds + wpack ----
    prep_kernel<<<dim3(6478), blk, 0, stream>>>(x, seg, w1_1, w2_1, XPh, start, WP);

    // Layer 1 (fused gather + GEMM): h1 = [A@X | X] @ WP + b
    fused1_kernel<<<dim3(MB), dim3(512), 0, stream>>>(x, XPh, rowptr, packed, WP, b_1, B);
    // Layer 2: relu(h1)(128) -> 64; HW1 fp16
    dense2_kernel<<<dim3(MB), dim3(512), 0, stream>>>(B, w1_2, w2_2, b_2, H2h, A2);
    spmm_h<64><<<dim3((N_NODES + 31) / 32), blk, 0, stream>>>(H2h, rowptr, packed, A2);
    // Layer 3: relu(h2)(64) -> 32; HW1 fp16
    dense3_kernel<<<dim3(MB), blk, 0, stream>>>(A2, w1_3, w2_3, b_3, H3h, B2);
    spmm_h<32><<<dim3(MB), blk, 0, stream>>>(H3h, rowptr, packed, B2);

    // Pool + head (fused, atomic-free)
    pool_kernel<<<dim3(N_GRAPHS), blk, 0, stream>>>(B2, start, wd, bd, (float*)d_out);
}

// Round 13
// 256.157 us; speedup vs baseline: 1.6759x; 1.0501x over previous
//
#include <hip/hip_runtime.h>
#include <hip/hip_fp16.h>

#define N_NODES 50000
#define N_EDGES 800000
#define N_GRAPHS 256
#define NCB 196        // coarse buckets = ceil(50000/256), dst>>8
#define CHUNK 3125     // edges per block in coarse passes (256 blocks)

// ---------------------------------------------------------------------------
// hist_prep: blocks 0..255 do the coarse edge histogram (dst>>8); blocks
// 256..6733 do the independent prep work (pad XPh/CI, bounds, wpack).
// Merged because both are embarrassingly parallel (saves one dispatch).
// ---------------------------------------------------------------------------
__global__ __launch_bounds__(256)
void hist_prep(const int* __restrict__ ER, const float* __restrict__ X,
               const int* __restrict__ SEG, const float* __restrict__ W1,
               const float* __restrict__ W2, int* __restrict__ ghist,
               __half* __restrict__ XPh, float* __restrict__ CI,
               int* __restrict__ start, float* __restrict__ WP)
{
    int b = blockIdx.x;
    int t = threadIdx.x;
    if (b < 256) {                           // coarse histogram
        __shared__ int h[NCB];
        for (int i = t; i < NCB; i += 256) h[i] = 0;
        __syncthreads();
        int lo = b * CHUNK, hi = lo + CHUNK;
        for (int e = lo + t; e < hi; e += 256) atomicAdd(&h[ER[e] >> 8], 1);
        __syncthreads();
        for (int i = t; i < NCB; i += 256) ghist[i * 256 + b] = h[i];
        return;
    }
    int bid = b - 256;
    if (bid < 6250) {                        // pad: XPh fp16 + CI cols 32..63
        int idx = bid * 256 + t;
        int n = idx >> 5;
        int c = idx & 31;
        float v = (c < 30) ? X[n * 30 + c] : 0.f;
        XPh[(size_t)n * 32 + c] = __float2half(v);
        CI[(size_t)n * 64 + 32 + c] = v;
    } else if (bid < 6250 + 196) {           // bounds from sorted seg
        int n = (bid - 6250) * 256 + t;
        if (n >= N_NODES) return;
        int g = SEG[n];
        int gprev = (n == 0) ? -1 : SEG[n - 1];
        for (int gg = gprev + 1; gg <= g; ++gg) start[gg] = n;
        if (n == N_NODES - 1)
            for (int gg = g + 1; gg <= N_GRAPHS; ++gg) start[gg] = N_NODES;
    } else {                                 // wpack: 64 x 128
        int idx = (bid - 6446) * 256 + t;
        if (idx >= 64 * 128) return;
        int k = idx >> 7, c = idx & 127;
        float w = 0.f;
        if (k < 30) w = W1[k * 128 + c];
        else if (k >= 32 && k < 62) w = W2[(k - 32) * 128 + c];
        WP[idx] = w;
    }
}

// ---------------------------------------------------------------------------
// scan1: per-bucket (196 blocks) exclusive scan of the 256 per-block counts,
// in place; bucket total -> bsum[b].
// ---------------------------------------------------------------------------
__global__ __launch_bounds__(256)
void scan1(int* __restrict__ ghist, int* __restrict__ bsum)
{
    __shared__ int s[256];
    int t = threadIdx.x, b = blockIdx.x;
    int i = b * 256 + t;
    int v = ghist[i];
    s[t] = v;
    __syncthreads();
    for (int off = 1; off < 256; off <<= 1) {
        int u = (t >= off) ? s[t - off] : 0;
        __syncthreads();
        s[t] += u;
        __syncthreads();
    }
    ghist[i] = s[t] - v;                 // within-bucket exclusive
    if (t == 255) bsum[b] = s[255];      // bucket total
}

// ---------------------------------------------------------------------------
// c_scatter: coarse scatter into per-block contiguous runs. Bucket base
// offsets computed locally (196-entry LDS scan of bsum).
// Record: x = src | ((dst&255)<<16), y = w bits.
// ---------------------------------------------------------------------------
__global__ __launch_bounds__(256)
void c_scatter(const int* __restrict__ ER, const int* __restrict__ EC,
               const float* __restrict__ EW, const int* __restrict__ ghist,
               const int* __restrict__ bsum, int2* __restrict__ tmp)
{
    __shared__ int s[256];
    __shared__ int cur[NCB];
    int t = threadIdx.x, blk = blockIdx.x;
    int v = (t < NCB) ? bsum[t] : 0;
    s[t] = v;
    __syncthreads();
    for (int off = 1; off < 256; off <<= 1) {
        int u = (t >= off) ? s[t - off] : 0;
        __syncthreads();
        s[t] += u;
        __syncthreads();
    }
    if (t < NCB) cur[t] = (s[t] - v) + ghist[t * 256 + blk];
    __syncthreads();
    int lo = blk * CHUNK, hi = lo + CHUNK;
    for (int e = lo + t; e < hi; e += 256) {
        int d = ER[e];
        int pos = atomicAdd(&cur[d >> 8], 1);
        tmp[pos] = make_int2(EC[e] | ((d & 255) << 16), __float_as_int(EW[e]));
    }
}

// ---------------------------------------------------------------------------
// bsort: per-bucket counting sort by dst&255 -> packed (src,w) + rowptr.
// ---------------------------------------------------------------------------
__global__ __launch_bounds__(256)
void bsort(const int2* __restrict__ tmp, const int* __restrict__ bsum,
           int2* __restrict__ packed, int* __restrict__ rowptr)
{
    __shared__ int s[256];
    __shared__ int hist[256];
    __shared__ int cur[256];
    int t = threadIdx.x, b = blockIdx.x;
    int v = (t < NCB) ? bsum[t] : 0;
    s[t] = v;
    __syncthreads();
    for (int off = 1; off < 256; off <<= 1) {
        int u = (t >= off) ? s[t - off] : 0;
        __syncthreads();
        s[t] += u;
        __syncthreads();
    }
    int cntb = bsum[b];
    int base = s[b] - cntb;
    int end  = base + cntb;
    __syncthreads();

    hist[t] = 0;
    __syncthreads();
    for (int j = base + t; j < end; j += 256)
        atomicAdd(&hist[(tmp[j].x >> 16) & 255], 1);
    __syncthreads();
    int hv = hist[t];
    s[t] = hv;
    __syncthreads();
    for (int off = 1; off < 256; off <<= 1) {
        int u = (t >= off) ? s[t - off] : 0;
        __syncthreads();
        s[t] += u;
        __syncthreads();
    }
    int excl = s[t] - hv;
    int n = b * 256 + t;
    if (n < N_NODES) rowptr[n] = base + excl;
    if (b == NCB - 1 && t == 0) rowptr[N_NODES] = N_EDGES;
    cur[t] = base + excl;
    __syncthreads();
    for (int j = base + t; j < end; j += 256) {
        int2 r = tmp[j];
        int pos = atomicAdd(&cur[(r.x >> 16) & 255], 1);
        packed[pos] = make_int2(r.x & 0xFFFF, r.y);
    }
}

// ---------------------------------------------------------------------------
// Dense GEMM core: lane = row, wave owns 16 cols, B via scalar path.
// ---------------------------------------------------------------------------
template<int K>
__device__ __forceinline__ void gemm16(const float* arow,
                                       const float* __restrict__ Wcol,
                                       int wstride, float acc[16])
{
    #pragma unroll
    for (int j = 0; j < 16; ++j) acc[j] = 0.f;
    for (int k = 0; k < K; k += 4) {
        float4 a = *(const float4*)(arow + k);
        float av[4] = {a.x, a.y, a.z, a.w};
        #pragma unroll
        for (int kk = 0; kk < 4; ++kk) {
            const float* wr = Wcol + (k + kk) * wstride;   // uniform address
            #pragma unroll
            for (int j = 0; j < 16; ++j)
                acc[j] = fmaf(av[kk], wr[j], acc[j]);
        }
    }
}

__device__ __forceinline__ void store16f(float* orow, const float acc[16],
                                         const float* __restrict__ Bcol)
{
    #pragma unroll
    for (int j4 = 0; j4 < 4; ++j4) {
        float4 v = make_float4(acc[j4*4+0], acc[j4*4+1], acc[j4*4+2], acc[j4*4+3]);
        if (Bcol) {
            float4 b = *(const float4*)(Bcol + j4 * 4);
            v.x += b.x; v.y += b.y; v.z += b.z; v.w += b.w;
        }
        *(float4*)(orow + j4 * 4) = v;
    }
}

__device__ __forceinline__ void store16h(__half* orow, const float acc[16])
{
    __half2 hb[8];
    #pragma unroll
    for (int j = 0; j < 8; ++j)
        hb[j] = __float22half2_rn(make_float2(acc[2*j], acc[2*j+1]));
    *(uint4*)(orow)     = *(uint4*)&hb[0];
    *(uint4*)(orow + 8) = *(uint4*)&hb[4];
}

// Layer 1: CI (N x 64) @ WP (64 x 128) + b -> H1 fp32 (N x 128). 8 waves.
__global__ __launch_bounds__(512)
void dense1_kernel(const float* __restrict__ CI, const float* __restrict__ WP,
                   const float* __restrict__ Bias, float* __restrict__ H1)
{
    __shared__ float As[64 * 68];
    const int m0 = blockIdx.x * 64;
    for (int i = threadIdx.x * 4; i < 64 * 64; i += 512 * 4) {
        int row = i >> 6, col = i & 63;
        int gm = m0 + row;
        float4 v = make_float4(0.f, 0.f, 0.f, 0.f);
        if (gm < N_NODES) v = *(const float4*)(CI + (size_t)gm * 64 + col);
        *(float4*)(As + row * 68 + col) = v;
    }
    __syncthreads();
    int wid = __builtin_amdgcn_readfirstlane(threadIdx.x >> 6);
    int lane = threadIdx.x & 63;
    float acc[16];
    gemm16<64>(As + lane * 68, WP + wid * 16, 128, acc);
    int gm = m0 + lane;
    if (gm < N_NODES)
        store16f(H1 + (size_t)gm * 128 + wid * 16, acc, Bias + wid * 16);
}

// Layer 2: relu(h1) (N x 128); waves 0-3 -> W1 -> HW1 fp16, 4-7 -> W2 -> AGG fp32+b.
__global__ __launch_bounds__(512)
void dense2_kernel(const float* __restrict__ X, const float* __restrict__ W1,
                   const float* __restrict__ W2, const float* __restrict__ Bias,
                   __half* __restrict__ HW1h, float* __restrict__ AGG)
{
    __shared__ float As[64 * 132];
    const int m0 = blockIdx.x * 64;
    for (int i = threadIdx.x * 4; i < 64 * 128; i += 512 * 4) {
        int row = i >> 7, col = i & 127;
        int gm = m0 + row;
        float4 v = make_float4(0.f, 0.f, 0.f, 0.f);
        if (gm < N_NODES) v = *(const float4*)(X + (size_t)gm * 128 + col);
        v.x = fmaxf(v.x, 0.f); v.y = fmaxf(v.y, 0.f);
        v.z = fmaxf(v.z, 0.f); v.w = fmaxf(v.w, 0.f);
        *(float4*)(As + row * 132 + col) = v;
    }
    __syncthreads();
    int wid = __builtin_amdgcn_readfirstlane(threadIdx.x >> 6);
    int lane = threadIdx.x & 63;
    const float* Wc = (wid < 4) ? (W1 + wid * 16) : (W2 + (wid - 4) * 16);
    float acc[16];
    gemm16<128>(As + lane * 132, Wc, 64, acc);
    int gm = m0 + lane;
    if (gm < N_NODES) {
        if (wid < 4)
            store16h(HW1h + (size_t)gm * 64 + wid * 16, acc);
        else
            store16f(AGG + (size_t)gm * 64 + (wid - 4) * 16, acc,
                     Bias + (wid - 4) * 16);
    }
}

// Layer 3: relu(h2) (N x 64); waves 0-1 -> W1 -> HW1 fp16, 2-3 -> W2 -> AGG fp32+b.
__global__ __launch_bounds__(256)
void dense3_kernel(const float* __restrict__ X, const float* __restrict__ W1,
                   const float* __restrict__ W2, const float* __restrict__ Bias,
                   __half* __restrict__ HW1h, float* __restrict__ AGG)
{
    __shared__ float As[64 * 68];
    const int m0 = blockIdx.x * 64;
    for (int i = threadIdx.x * 4; i < 64 * 64; i += 256 * 4) {
        int row = i >> 6, col = i & 63;
        int gm = m0 + row;
        float4 v = make_float4(0.f, 0.f, 0.f, 0.f);
        if (gm < N_NODES) v = *(const float4*)(X + (size_t)gm * 64 + col);
        v.x = fmaxf(v.x, 0.f); v.y = fmaxf(v.y, 0.f);
        v.z = fmaxf(v.z, 0.f); v.w = fmaxf(v.w, 0.f);
        *(float4*)(As + row * 68 + col) = v;
    }
    __syncthreads();
    int wid = __builtin_amdgcn_readfirstlane(threadIdx.x >> 6);
    int lane = threadIdx.x & 63;
    const float* Wc = (wid < 2) ? (W1 + wid * 16) : (W2 + (wid - 2) * 16);
    float acc[16];
    gemm16<64>(As + lane * 68, Wc, 32, acc);
    int gm = m0 + lane;
    if (gm < N_NODES) {
        if (wid < 2)
            store16h(HW1h + (size_t)gm * 32 + wid * 16, acc);
        else
            store16f(AGG + (size_t)gm * 32 + (wid - 2) * 16, acc,
                     Bias + (wid - 2) * 16);
    }
}

// ---------------------------------------------------------------------------
// aggx_h: CI[n][0..31] = sum_j w_j * fp16 XPh[src_j][0..31]  (A @ X)
// ---------------------------------------------------------------------------
__global__ __launch_bounds__(256)
void aggx_h(const __half* __restrict__ XPh, const int* __restrict__ rowptr,
            const int2* __restrict__ packed, float* __restrict__ CI)
{
    int tid = threadIdx.x;
    int local = tid >> 2;
    int q = tid & 3;
    int n = blockIdx.x * 64 + local;
    if (n >= N_NODES) return;
    int r0 = rowptr[n], r1 = rowptr[n + 1];
    float4 acc0 = make_float4(0.f, 0.f, 0.f, 0.f);
    float4 acc1 = make_float4(0.f, 0.f, 0.f, 0.f);
    for (int j = r0; j < r1; ++j) {
        int2 r = packed[j];
        float w = __int_as_float(r.y);
        uint4 raw = *(const uint4*)(XPh + (size_t)r.x * 32 + q * 8);
        const __half2* hp = (const __half2*)&raw;
        float2 f0 = __half22float2(hp[0]);
        float2 f1 = __half22float2(hp[1]);
        float2 f2 = __half22float2(hp[2]);
        float2 f3 = __half22float2(hp[3]);
        acc0.x = fmaf(w, f0.x, acc0.x); acc0.y = fmaf(w, f0.y, acc0.y);
        acc0.z = fmaf(w, f1.x, acc0.z); acc0.w = fmaf(w, f1.y, acc0.w);
        acc1.x = fmaf(w, f2.x, acc1.x); acc1.y = fmaf(w, f2.y, acc1.y);
        acc1.z = fmaf(w, f3.x, acc1.z); acc1.w = fmaf(w, f3.y, acc1.w);
    }
    float* op = CI + (size_t)n * 64 + q * 8;
    *(float4*)op = acc0;
    *(float4*)(op + 4) = acc1;
}

// ---------------------------------------------------------------------------
// spmm_h (layers 2,3): fp16 gather rows, fp32 accumulate on top of AGG.
// ---------------------------------------------------------------------------
template<int FOUT>
__global__ __launch_bounds__(256)
void spmm_h(const __half* __restrict__ H, const int* __restrict__ rowptr,
            const int2* __restrict__ packed, float* __restrict__ AGG)
{
    constexpr int T = FOUT / 8;
    int tid = threadIdx.x;
    int local = tid / T;
    int q = tid % T;
    int n = blockIdx.x * (256 / T) + local;
    if (n >= N_NODES) return;
    int r0 = rowptr[n], r1 = rowptr[n + 1];
    float* ap = AGG + (size_t)n * FOUT + q * 8;
    float4 acc0 = *(const float4*)ap;
    float4 acc1 = *(const float4*)(ap + 4);
    for (int j = r0; j < r1; ++j) {
        int2 r = packed[j];
        float w = __int_as_float(r.y);
        uint4 raw = *(const uint4*)(H + (size_t)r.x * FOUT + q * 8);
        const __half2* hp = (const __half2*)&raw;
        float2 f0 = __half22float2(hp[0]);
        float2 f1 = __half22float2(hp[1]);
        float2 f2 = __half22float2(hp[2]);
        float2 f3 = __half22float2(hp[3]);
        acc0.x = fmaf(w, f0.x, acc0.x); acc0.y = fmaf(w, f0.y, acc0.y);
        acc0.z = fmaf(w, f1.x, acc0.z); acc0.w = fmaf(w, f1.y, acc0.w);
        acc1.x = fmaf(w, f2.x, acc1.x); acc1.y = fmaf(w, f2.y, acc1.y);
        acc1.z = fmaf(w, f3.x, acc1.z); acc1.w = fmaf(w, f3.y, acc1.w);
    }
    *(float4*)ap = acc0;
    *(float4*)(ap + 4) = acc1;
}

// ---------------------------------------------------------------------------
// pool + head fused: one block/graph; mean of relu(H) then softmax(p@wd+bd).
// ---------------------------------------------------------------------------
__global__ __launch_bounds__(256)
void pool_kernel(const float* __restrict__ H, const int* __restrict__ start,
                 const float* __restrict__ WD, const float* __restrict__ BD,
                 float* __restrict__ OUT)
{
    __shared__ float red[8][33];
    int g = blockIdx.x;
    int s = start[g], e = start[g + 1];
    int q = threadIdx.x & 31;
    int lane = threadIdx.x >> 5;
    float acc = 0.f;
    for (int n = s + lane; n < e; n += 8)
        acc += fmaxf(H[(size_t)n * 32 + q], 0.f);
    red[lane][q] = acc;
    __syncthreads();
    if (threadIdx.x < 32) {
        float v = 0.f;
        #pragma unroll
        for (int i = 0; i < 8; ++i) v += red[i][q];
        float inv = (e > s) ? 1.0f / (float)(e - s) : 1.0f;
        float p = v * inv;
        float p0 = p * WD[q * 2 + 0];
        float p1 = p * WD[q * 2 + 1];
        #pragma unroll
        for (int off = 16; off; off >>= 1) {
            p0 += __shfl_down(p0, off, 32);
            p1 += __shfl_down(p1, off, 32);
        }
        if (q == 0) {
            float l0 = p0 + BD[0], l1 = p1 + BD[1];
            float m = fmaxf(l0, l1);
            float e0 = expf(l0 - m), e1 = expf(l1 - m);
            float si = 1.0f / (e0 + e1);
            OUT[g * 2 + 0] = e0 * si;
            OUT[g * 2 + 1] = e1 * si;
        }
    }
}

extern "C" void kernel_launch(void* const* d_in, const int* in_sizes, int n_in,
                              void* d_out, int out_size, void* d_ws, size_t ws_size,
                              hipStream_t stream)
{
    const float* x    = (const float*)d_in[0];
    const float* ew   = (const float*)d_in[1];
    const int*   er   = (const int*)d_in[2];
    const int*   ec   = (const int*)d_in[3];
    const int*   seg  = (const int*)d_in[4];
    const float* w1_1 = (const float*)d_in[5];
    const float* w2_1 = (const float*)d_in[6];
    const float* b_1  = (const float*)d_in[7];
    const float* w1_2 = (const float*)d_in[8];
    const float* w2_2 = (const float*)d_in[9];
    const float* b_2  = (const float*)d_in[10];
    const float* w1_3 = (const float*)d_in[11];
    const float* w2_3 = (const float*)d_in[12];
    const float* b_3  = (const float*)d_in[13];
    const float* wd   = (const float*)d_in[14];
    const float* bd   = (const float*)d_in[15];

    float* ws = (float*)d_ws;
    // Phase 1: CI fp32 (0..3.2M), XPh fp16 (3.2M..4.0M), B=h1 fp32 (6.4..12.8M)
    float*  CI   = ws;                         // N x 64 fp32
    __half* XPh  = (__half*)(ws + 3200000);    // N x 32 fp16
    float*  B    = ws + 6400000;               // N x 128 fp32 (h1)
    int2*   tmp  = (int2*)(ws + 6400000);      // E x int2 (CSR build; dead before h1)
    // Phase 2: H2h fp16 at 0 (CI dead), A2=h2 fp32 at 3.2M (XPh dead)
    __half* H2h  = (__half*)ws;                // N x 64 fp16
    float*  A2   = ws + 3200000;               // N x 64 fp32 (h2)
    // Phase 3: H3h fp16 at 6.4M (B dead), B2=h3 fp32 at 8.0M
    __half* H3h  = (__half*)(ws + 6400000);    // N x 32 fp16
    float*  B2   = ws + 8000000;               // N x 32 fp32 (h3)
    int*    IW   = (int*)d_ws;
    int2*   packed = (int2*)(IW + 12800000);   // E x {src, w}
    int*    rowptr = IW + 14400000;            // N+1
    int*    ghist  = IW + 14460000;            // NCB*256
    int*    bsum   = IW + 14515000;            // NCB
    int*    start  = IW + 14520000;            // G+1
    float*  WP     = ws + 14540000;            // 64 x 128 packed layer-1 weights

    dim3 blk(256);
    const int MB = (N_NODES + 63) / 64;        // 782

    // ---- CSR build + prep: hist(256) + prep(6478) merged -> scan -> scatter -> sort ----
    hist_prep<<<dim3(256 + 6478), blk, 0, stream>>>(er, x, seg, w1_1, w2_1,
                                                    ghist, XPh, CI, start, WP);
    scan1<<<dim3(NCB), blk, 0, stream>>>(ghist, bsum);
    c_scatter<<<dim3(256), blk, 0, stream>>>(er, ec, ew, ghist, bsum, tmp);
    bsort<<<dim3(NCB), blk, 0, stream>>>(tmp, bsum, packed, rowptr);

    // Layer 1: CI = [A@X | X], h1 = CI @ WP + b  (separate, full-occupancy)
    aggx_h<<<dim3(MB), blk, 0, stream>>>(XPh, rowptr, packed, CI);
    dense1_kernel<<<dim3(MB), dim3(512), 0, stream>>>(CI, WP, b_1, B);
    // Layer 2: relu(h1)(128) -> 64; HW1 fp16
    dense2_kernel<<<dim3(MB), dim3(512), 0, stream>>>(B, w1_2, w2_2, b_2, H2h, A2);
    spmm_h<64><<<dim3((N_NODES + 31) / 32), blk, 0, stream>>>(H2h, rowptr, packed, A2);
    // Layer 3: relu(h2)(64) -> 32; HW1 fp16
    dense3_kernel<<<dim3(MB), blk, 0, stream>>>(A2, w1_3, w2_3, b_3, H3h, B2);
    spmm_h<32><<<dim3(MB), blk, 0, stream>>>(H3h, rowptr, packed, B2);

    // Pool + head (fused, atomic-free)
    pool_kernel<<<dim3(N_GRAPHS), blk, 0, stream>>>(B2, start, wd, bd, (float*)d_out);
}

// Round 14
// 244.013 us; speedup vs baseline: 1.7594x; 1.0498x over previous
//
#include <hip/hip_runtime.h>
#include <hip/hip_fp16.h>

#define N_NODES 50000
#define N_EDGES 800000
#define N_GRAPHS 256
#define NCB 196        // coarse buckets = ceil(50000/256), dst>>8
#define CHUNK 3125     // edges per block in coarse passes (256 blocks)

// ---------------------------------------------------------------------------
// hist_prep: blocks 0..255 coarse edge histogram (dst>>8); blocks 256..6733
// independent prep (pad XPh/CI, bounds, wpack). Merged: both fully parallel.
// ---------------------------------------------------------------------------
__global__ __launch_bounds__(256)
void hist_prep(const int* __restrict__ ER, const float* __restrict__ X,
               const int* __restrict__ SEG, const float* __restrict__ W1,
               const float* __restrict__ W2, int* __restrict__ ghist,
               __half* __restrict__ XPh, float* __restrict__ CI,
               int* __restrict__ start, float* __restrict__ WP)
{
    int b = blockIdx.x;
    int t = threadIdx.x;
    if (b < 256) {                           // coarse histogram
        __shared__ int h[NCB];
        for (int i = t; i < NCB; i += 256) h[i] = 0;
        __syncthreads();
        int lo = b * CHUNK, hi = lo + CHUNK;
        for (int e = lo + t; e < hi; e += 256) atomicAdd(&h[ER[e] >> 8], 1);
        __syncthreads();
        for (int i = t; i < NCB; i += 256) ghist[i * 256 + b] = h[i];
        return;
    }
    int bid = b - 256;
    if (bid < 6250) {                        // pad: XPh fp16 + CI cols 32..63
        int idx = bid * 256 + t;
        int n = idx >> 5;
        int c = idx & 31;
        float v = (c < 30) ? X[n * 30 + c] : 0.f;
        XPh[(size_t)n * 32 + c] = __float2half(v);
        CI[(size_t)n * 64 + 32 + c] = v;
    } else if (bid < 6250 + 196) {           // bounds from sorted seg
        int n = (bid - 6250) * 256 + t;
        if (n >= N_NODES) return;
        int g = SEG[n];
        int gprev = (n == 0) ? -1 : SEG[n - 1];
        for (int gg = gprev + 1; gg <= g; ++gg) start[gg] = n;
        if (n == N_NODES - 1)
            for (int gg = g + 1; gg <= N_GRAPHS; ++gg) start[gg] = N_NODES;
    } else {                                 // wpack: 64 x 128
        int idx = (bid - 6446) * 256 + t;
        if (idx >= 64 * 128) return;
        int k = idx >> 7, c = idx & 127;
        float w = 0.f;
        if (k < 30) w = W1[k * 128 + c];
        else if (k >= 32 && k < 62) w = W2[(k - 32) * 128 + c];
        WP[idx] = w;
    }
}

// ---------------------------------------------------------------------------
// scan1: per-bucket exclusive scan of the 256 per-block counts, in place;
// bucket total -> bsum[b].
// ---------------------------------------------------------------------------
__global__ __launch_bounds__(256)
void scan1(int* __restrict__ ghist, int* __restrict__ bsum)
{
    __shared__ int s[256];
    int t = threadIdx.x, b = blockIdx.x;
    int i = b * 256 + t;
    int v = ghist[i];
    s[t] = v;
    __syncthreads();
    for (int off = 1; off < 256; off <<= 1) {
        int u = (t >= off) ? s[t - off] : 0;
        __syncthreads();
        s[t] += u;
        __syncthreads();
    }
    ghist[i] = s[t] - v;
    if (t == 255) bsum[b] = s[255];
}

// ---------------------------------------------------------------------------
// c_scatter: coarse scatter into per-block contiguous runs. tmp record:
// x = src | ((dst&255)<<16), y = fp32 weight bits.
// ---------------------------------------------------------------------------
__global__ __launch_bounds__(256)
void c_scatter(const int* __restrict__ ER, const int* __restrict__ EC,
               const float* __restrict__ EW, const int* __restrict__ ghist,
               const int* __restrict__ bsum, int2* __restrict__ tmp)
{
    __shared__ int s[256];
    __shared__ int cur[NCB];
    int t = threadIdx.x, blk = blockIdx.x;
    int v = (t < NCB) ? bsum[t] : 0;
    s[t] = v;
    __syncthreads();
    for (int off = 1; off < 256; off <<= 1) {
        int u = (t >= off) ? s[t - off] : 0;
        __syncthreads();
        s[t] += u;
        __syncthreads();
    }
    if (t < NCB) cur[t] = (s[t] - v) + ghist[t * 256 + blk];
    __syncthreads();
    int lo = blk * CHUNK, hi = lo + CHUNK;
    for (int e = lo + t; e < hi; e += 256) {
        int d = ER[e];
        int pos = atomicAdd(&cur[d >> 8], 1);
        tmp[pos] = make_int2(EC[e] | ((d & 255) << 16), __float_as_int(EW[e]));
    }
}

// ---------------------------------------------------------------------------
// bsort: per-bucket counting sort by dst&255 -> packed 4B records
// (src16 | fp16w<<16) + rowptr.
// ---------------------------------------------------------------------------
__global__ __launch_bounds__(256)
void bsort(const int2* __restrict__ tmp, const int* __restrict__ bsum,
           unsigned int* __restrict__ packed, int* __restrict__ rowptr)
{
    __shared__ int s[256];
    __shared__ int hist[256];
    __shared__ int cur[256];
    int t = threadIdx.x, b = blockIdx.x;
    int v = (t < NCB) ? bsum[t] : 0;
    s[t] = v;
    __syncthreads();
    for (int off = 1; off < 256; off <<= 1) {
        int u = (t >= off) ? s[t - off] : 0;
        __syncthreads();
        s[t] += u;
        __syncthreads();
    }
    int cntb = bsum[b];
    int base = s[b] - cntb;
    int end  = base + cntb;
    __syncthreads();

    hist[t] = 0;
    __syncthreads();
    for (int j = base + t; j < end; j += 256)
        atomicAdd(&hist[(tmp[j].x >> 16) & 255], 1);
    __syncthreads();
    int hv = hist[t];
    s[t] = hv;
    __syncthreads();
    for (int off = 1; off < 256; off <<= 1) {
        int u = (t >= off) ? s[t - off] : 0;
        __syncthreads();
        s[t] += u;
        __syncthreads();
    }
    int excl = s[t] - hv;
    int n = b * 256 + t;
    if (n < N_NODES) rowptr[n] = base + excl;
    if (b == NCB - 1 && t == 0) rowptr[N_NODES] = N_EDGES;
    cur[t] = base + excl;
    __syncthreads();
    for (int j = base + t; j < end; j += 256) {
        int2 r = tmp[j];
        int pos = atomicAdd(&cur[(r.x >> 16) & 255], 1);
        unsigned short hb = __half_as_ushort(__float2half(__int_as_float(r.y)));
        packed[pos] = (unsigned int)(r.x & 0xFFFF) | ((unsigned int)hb << 16);
    }
}

// ---------------------------------------------------------------------------
// Dense GEMM core: lane = row, wave owns 16 cols, B via scalar path.
// ---------------------------------------------------------------------------
template<int K>
__device__ __forceinline__ void gemm16(const float* arow,
                                       const float* __restrict__ Wcol,
                                       int wstride, float acc[16])
{
    #pragma unroll
    for (int j = 0; j < 16; ++j) acc[j] = 0.f;
    for (int k = 0; k < K; k += 4) {
        float4 a = *(const float4*)(arow + k);
        float av[4] = {a.x, a.y, a.z, a.w};
        #pragma unroll
        for (int kk = 0; kk < 4; ++kk) {
            const float* wr = Wcol + (k + kk) * wstride;   // uniform address
            #pragma unroll
            for (int j = 0; j < 16; ++j)
                acc[j] = fmaf(av[kk], wr[j], acc[j]);
        }
    }
}

__device__ __forceinline__ void addbias16(float acc[16],
                                          const float* __restrict__ Bcol)
{
    #pragma unroll
    for (int j4 = 0; j4 < 4; ++j4) {
        float4 bb = *(const float4*)(Bcol + j4 * 4);
        acc[j4*4+0] += bb.x; acc[j4*4+1] += bb.y;
        acc[j4*4+2] += bb.z; acc[j4*4+3] += bb.w;
    }
}

__device__ __forceinline__ void store16h(__half* orow, const float acc[16])
{
    __half2 hb[8];
    #pragma unroll
    for (int j = 0; j < 8; ++j)
        hb[j] = __float22half2_rn(make_float2(acc[2*j], acc[2*j+1]));
    *(uint4*)(orow)     = *(uint4*)&hb[0];
    *(uint4*)(orow + 8) = *(uint4*)&hb[4];
}

// fp16 input staging into fp32 LDS tile (stride K+4), optional relu.
template<int K, int TPB, bool RELU>
__device__ __forceinline__ void stage_Ah(const __half* __restrict__ X,
                                         float* As, int m0)
{
    constexpr int KP = K + 4;
    for (int i = threadIdx.x * 4; i < 64 * K; i += TPB * 4) {
        int row = i / K;
        int col = i % K;
        int gm = m0 + row;
        float4 v = make_float4(0.f, 0.f, 0.f, 0.f);
        if (gm < N_NODES) {
            uint2 raw = *(const uint2*)(X + (size_t)gm * K + col);
            const __half2* hp = (const __half2*)&raw;
            float2 f0 = __half22float2(hp[0]);
            float2 f1 = __half22float2(hp[1]);
            v = make_float4(f0.x, f0.y, f1.x, f1.y);
        }
        if (RELU) {
            v.x = fmaxf(v.x, 0.f); v.y = fmaxf(v.y, 0.f);
            v.z = fmaxf(v.z, 0.f); v.w = fmaxf(v.w, 0.f);
        }
        *(float4*)(As + row * KP + col) = v;
    }
    __syncthreads();
}

// Layer 1: CI fp32 (N x 64) @ WP (64 x 128) + b -> H1h fp16 (N x 128). 8 waves.
__global__ __launch_bounds__(512)
void dense1_kernel(const float* __restrict__ CI, const float* __restrict__ WP,
                   const float* __restrict__ Bias, __half* __restrict__ H1h)
{
    __shared__ float As[64 * 68];
    const int m0 = blockIdx.x * 64;
    for (int i = threadIdx.x * 4; i < 64 * 64; i += 512 * 4) {
        int row = i >> 6, col = i & 63;
        int gm = m0 + row;
        float4 v = make_float4(0.f, 0.f, 0.f, 0.f);
        if (gm < N_NODES) v = *(const float4*)(CI + (size_t)gm * 64 + col);
        *(float4*)(As + row * 68 + col) = v;
    }
    __syncthreads();
    int wid = __builtin_amdgcn_readfirstlane(threadIdx.x >> 6);
    int lane = threadIdx.x & 63;
    float acc[16];
    gemm16<64>(As + lane * 68, WP + wid * 16, 128, acc);
    int gm = m0 + lane;
    if (gm < N_NODES) {
        addbias16(acc, Bias + wid * 16);
        store16h(H1h + (size_t)gm * 128 + wid * 16, acc);
    }
}

// Layer 2: relu(h1h) (N x 128 fp16); waves 0-3 -> W1 -> H2h, 4-7 -> W2 -> A2h (+b).
__global__ __launch_bounds__(512)
void dense2_kernel(const __half* __restrict__ X, const float* __restrict__ W1,
                   const float* __restrict__ W2, const float* __restrict__ Bias,
                   __half* __restrict__ HW1h, __half* __restrict__ AGGh)
{
    __shared__ float As[64 * 132];
    const int m0 = blockIdx.x * 64;
    stage_Ah<128, 512, true>(X, As, m0);
    int wid = __builtin_amdgcn_readfirstlane(threadIdx.x >> 6);
    int lane = threadIdx.x & 63;
    const float* Wc = (wid < 4) ? (W1 + wid * 16) : (W2 + (wid - 4) * 16);
    float acc[16];
    gemm16<128>(As + lane * 132, Wc, 64, acc);
    int gm = m0 + lane;
    if (gm < N_NODES) {
        if (wid < 4)
            store16h(HW1h + (size_t)gm * 64 + wid * 16, acc);
        else {
            addbias16(acc, Bias + (wid - 4) * 16);
            store16h(AGGh + (size_t)gm * 64 + (wid - 4) * 16, acc);
        }
    }
}

// Layer 3: relu(h2h) (N x 64 fp16); waves 0-1 -> W1 -> H3h, 2-3 -> W2 -> B2h (+b).
__global__ __launch_bounds__(256)
void dense3_kernel(const __half* __restrict__ X, const float* __restrict__ W1,
                   const float* __restrict__ W2, const float* __restrict__ Bias,
                   __half* __restrict__ HW1h, __half* __restrict__ AGGh)
{
    __shared__ float As[64 * 68];
    const int m0 = blockIdx.x * 64;
    stage_Ah<64, 256, true>(X, As, m0);
    int wid = __builtin_amdgcn_readfirstlane(threadIdx.x >> 6);
    int lane = threadIdx.x & 63;
    const float* Wc = (wid < 2) ? (W1 + wid * 16) : (W2 + (wid - 2) * 16);
    float acc[16];
    gemm16<64>(As + lane * 68, Wc, 32, acc);
    int gm = m0 + lane;
    if (gm < N_NODES) {
        if (wid < 2)
            store16h(HW1h + (size_t)gm * 32 + wid * 16, acc);
        else {
            addbias16(acc, Bias + (wid - 2) * 16);
            store16h(AGGh + (size_t)gm * 32 + (wid - 2) * 16, acc);
        }
    }
}

// ---------------------------------------------------------------------------
// aggx_h: CI[n][0..31] = sum_j w_j * XPh[src_j][0..31] (fp16 gather, 4B recs)
// ---------------------------------------------------------------------------
__global__ __launch_bounds__(256)
void aggx_h(const __half* __restrict__ XPh, const int* __restrict__ rowptr,
            const unsigned int* __restrict__ packed, float* __restrict__ CI)
{
    int tid = threadIdx.x;
    int local = tid >> 2;
    int q = tid & 3;
    int n = blockIdx.x * 64 + local;
    if (n >= N_NODES) return;
    int r0 = rowptr[n], r1 = rowptr[n + 1];
    float4 acc0 = make_float4(0.f, 0.f, 0.f, 0.f);
    float4 acc1 = make_float4(0.f, 0.f, 0.f, 0.f);
    for (int j = r0; j < r1; ++j) {
        unsigned int r = packed[j];
        float w = __half2float(__ushort_as_half((unsigned short)(r >> 16)));
        uint4 raw = *(const uint4*)(XPh + (size_t)(r & 0xFFFF) * 32 + q * 8);
        const __half2* hp = (const __half2*)&raw;
        float2 f0 = __half22float2(hp[0]);
        float2 f1 = __half22float2(hp[1]);
        float2 f2 = __half22float2(hp[2]);
        float2 f3 = __half22float2(hp[3]);
        acc0.x = fmaf(w, f0.x, acc0.x); acc0.y = fmaf(w, f0.y, acc0.y);
        acc0.z = fmaf(w, f1.x, acc0.z); acc0.w = fmaf(w, f1.y, acc0.w);
        acc1.x = fmaf(w, f2.x, acc1.x); acc1.y = fmaf(w, f2.y, acc1.y);
        acc1.z = fmaf(w, f3.x, acc1.z); acc1.w = fmaf(w, f3.y, acc1.w);
    }
    float* op = CI + (size_t)n * 64 + q * 8;
    *(float4*)op = acc0;
    *(float4*)(op + 4) = acc1;
}

// ---------------------------------------------------------------------------
// spmm_h: fp16 gather rows, fp32 accumulate on top of fp16 AGG (RMW), 4B recs.
// ---------------------------------------------------------------------------
template<int FOUT>
__global__ __launch_bounds__(256)
void spmm_h(const __half* __restrict__ H, const int* __restrict__ rowptr,
            const unsigned int* __restrict__ packed, __half* __restrict__ AGGh)
{
    constexpr int T = FOUT / 8;
    int tid = threadIdx.x;
    int local = tid / T;
    int q = tid % T;
    int n = blockIdx.x * (256 / T) + local;
    if (n >= N_NODES) return;
    int r0 = rowptr[n], r1 = rowptr[n + 1];
    __half* ap = AGGh + (size_t)n * FOUT + q * 8;
    float4 acc0, acc1;
    {
        uint4 raw = *(const uint4*)ap;
        const __half2* hp = (const __half2*)&raw;
        float2 f0 = __half22float2(hp[0]);
        float2 f1 = __half22float2(hp[1]);
        float2 f2 = __half22float2(hp[2]);
        float2 f3 = __half22float2(hp[3]);
        acc0 = make_float4(f0.x, f0.y, f1.x, f1.y);
        acc1 = make_float4(f2.x, f2.y, f3.x, f3.y);
    }
    for (int j = r0; j < r1; ++j) {
        unsigned int r = packed[j];
        float w = __half2float(__ushort_as_half((unsigned short)(r >> 16)));
        uint4 raw = *(const uint4*)(H + (size_t)(r & 0xFFFF) * FOUT + q * 8);
        const __half2* hp = (const __half2*)&raw;
        float2 f0 = __half22float2(hp[0]);
        float2 f1 = __half22float2(hp[1]);
        float2 f2 = __half22float2(hp[2]);
        float2 f3 = __half22float2(hp[3]);
        acc0.x = fmaf(w, f0.x, acc0.x); acc0.y = fmaf(w, f0.y, acc0.y);
        acc0.z = fmaf(w, f1.x, acc0.z); acc0.w = fmaf(w, f1.y, acc0.w);
        acc1.x = fmaf(w, f2.x, acc1.x); acc1.y = fmaf(w, f2.y, acc1.y);
        acc1.z = fmaf(w, f3.x, acc1.z); acc1.w = fmaf(w, f3.y, acc1.w);
    }
    __half2 hb[4];
    hb[0] = __float22half2_rn(make_float2(acc0.x, acc0.y));
    hb[1] = __float22half2_rn(make_float2(acc0.z, acc0.w));
    hb[2] = __float22half2_rn(make_float2(acc1.x, acc1.y));
    hb[3] = __float22half2_rn(make_float2(acc1.z, acc1.w));
    *(uint4*)ap = *(uint4*)&hb[0];
}

// ---------------------------------------------------------------------------
// pool + head fused: one block/graph; mean of relu(h3h fp16), softmax(p@wd+bd).
// ---------------------------------------------------------------------------
__global__ __launch_bounds__(256)
void pool_kernel(const __half* __restrict__ H, const int* __restrict__ start,
                 const float* __restrict__ WD, const float* __restrict__ BD,
                 float* __restrict__ OUT)
{
    __shared__ float red[8][33];
    int g = blockIdx.x;
    int s = start[g], e = start[g + 1];
    int q = threadIdx.x & 31;
    int lane = threadIdx.x >> 5;
    float acc = 0.f;
    for (int n = s + lane; n < e; n += 8)
        acc += fmaxf(__half2float(H[(size_t)n * 32 + q]), 0.f);
    red[lane][q] = acc;
    __syncthreads();
    if (threadIdx.x < 32) {
        float v = 0.f;
        #pragma unroll
        for (int i = 0; i < 8; ++i) v += red[i][q];
        float inv = (e > s) ? 1.0f / (float)(e - s) : 1.0f;
        float p = v * inv;
        float p0 = p * WD[q * 2 + 0];
        float p1 = p * WD[q * 2 + 1];
        #pragma unroll
        for (int off = 16; off; off >>= 1) {
            p0 += __shfl_down(p0, off, 32);
            p1 += __shfl_down(p1, off, 32);
        }
        if (q == 0) {
            float l0 = p0 + BD[0], l1 = p1 + BD[1];
            float m = fmaxf(l0, l1);
            float e0 = expf(l0 - m), e1 = expf(l1 - m);
            float si = 1.0f / (e0 + e1);
            OUT[g * 2 + 0] = e0 * si;
            OUT[g * 2 + 1] = e1 * si;
        }
    }
}

extern "C" void kernel_launch(void* const* d_in, const int* in_sizes, int n_in,
                              void* d_out, int out_size, void* d_ws, size_t ws_size,
                              hipStream_t stream)
{
    const float* x    = (const float*)d_in[0];
    const float* ew   = (const float*)d_in[1];
    const int*   er   = (const int*)d_in[2];
    const int*   ec   = (const int*)d_in[3];
    const int*   seg  = (const int*)d_in[4];
    const float* w1_1 = (const float*)d_in[5];
    const float* w2_1 = (const float*)d_in[6];
    const float* b_1  = (const float*)d_in[7];
    const float* w1_2 = (const float*)d_in[8];
    const float* w2_2 = (const float*)d_in[9];
    const float* b_2  = (const float*)d_in[10];
    const float* w1_3 = (const float*)d_in[11];
    const float* w2_3 = (const float*)d_in[12];
    const float* b_3  = (const float*)d_in[13];
    const float* wd   = (const float*)d_in[14];
    const float* bd   = (const float*)d_in[15];

    float* ws = (float*)d_ws;
    // Phase 1: CI fp32 (0..3.2M), XPh fp16 (3.2M..4.0M), H1h fp16 (6.4M..9.6M fl)
    float*  CI   = ws;                         // N x 64 fp32
    __half* XPh  = (__half*)(ws + 3200000);    // N x 32 fp16
    __half* H1h  = (__half*)(ws + 6400000);    // N x 128 fp16 (h1)
    int2*   tmp  = (int2*)(ws + 6400000);      // E x int2 (CSR build; dead before h1)
    // Phase 2: H2h at 0 (CI dead), A2h at 3.2M (XPh dead)
    __half* H2h  = (__half*)ws;                // N x 64 fp16
    __half* A2h  = (__half*)(ws + 3200000);    // N x 64 fp16 (h2)
    // Phase 3: H3h at 6.4M (H1h dead), B2h at 8.0M
    __half* H3h  = (__half*)(ws + 6400000);    // N x 32 fp16
    __half* B2h  = (__half*)(ws + 8000000);    // N x 32 fp16 (h3)
    int*    IW   = (int*)d_ws;
    unsigned int* packed = (unsigned int*)(IW + 12800000);  // E x 4B {src16|w16}
    int*    rowptr = IW + 14400000;            // N+1
    int*    ghist  = IW + 14460000;            // NCB*256
    int*    bsum   = IW + 14515000;            // NCB
    int*    start  = IW + 14520000;            // G+1
    float*  WP     = ws + 14540000;            // 64 x 128 packed layer-1 weights

    dim3 blk(256);
    const int MB = (N_NODES + 63) / 64;        // 782

    // ---- CSR build + prep: hist(256)+prep(6478) -> scan -> scatter -> sort ----
    hist_prep<<<dim3(256 + 6478), blk, 0, stream>>>(er, x, seg, w1_1, w2_1,
                                                    ghist, XPh, CI, start, WP);
    scan1<<<dim3(NCB), blk, 0, stream>>>(ghist, bsum);
    c_scatter<<<dim3(256), blk, 0, stream>>>(er, ec, ew, ghist, bsum, tmp);
    bsort<<<dim3(NCB), blk, 0, stream>>>(tmp, bsum, packed, rowptr);

    // Layer 1: CI = [A@X | X], h1h = CI @ WP + b
    aggx_h<<<dim3(MB), blk, 0, stream>>>(XPh, rowptr, packed, CI);
    dense1_kernel<<<dim3(MB), dim3(512), 0, stream>>>(CI, WP, b_1, H1h);
    // Layer 2: relu(h1h)(128) -> 64; both outputs fp16
    dense2_kernel<<<dim3(MB), dim3(512), 0, stream>>>(H1h, w1_2, w2_2, b_2, H2h, A2h);
    spmm_h<64><<<dim3((N_NODES + 31) / 32), blk, 0, stream>>>(H2h, rowptr, packed, A2h);
    // Layer 3: relu(h2h)(64) -> 32; both outputs fp16
    dense3_kernel<<<dim3(MB), blk, 0, stream>>>(A2h, w1_3, w2_3, b_3, H3h, B2h);
    spmm_h<32><<<dim3(MB), blk, 0, stream>>>(H3h, rowptr, packed, B2h);

    // Pool + head (fused, atomic-free)
    pool_kernel<<<dim3(N_GRAPHS), blk, 0, stream>>>(B2h, start, wd, bd, (float*)d_out);
}

// Round 15
// 229.796 us; speedup vs baseline: 1.8682x; 1.0619x over previous
//
#include <hip/hip_runtime.h>
#include <hip/hip_fp16.h>

#define N_NODES 50000
#define N_EDGES 800000
#define N_GRAPHS 256
#define NCB 196        // coarse buckets = ceil(50000/256), dst>>8
#define CHUNK 3125     // edges per block in coarse passes (256 blocks)

// ---------------------------------------------------------------------------
// hist_prep: blocks 0..255 coarse edge histogram (dst>>8); blocks 256..6733
// independent prep (pad XPh, bounds, wpack). Merged: both fully parallel.
// ---------------------------------------------------------------------------
__global__ __launch_bounds__(256)
void hist_prep(const int* __restrict__ ER, const float* __restrict__ X,
               const int* __restrict__ SEG, const float* __restrict__ W1,
               const float* __restrict__ W2, int* __restrict__ ghist,
               __half* __restrict__ XPh, int* __restrict__ start,
               float* __restrict__ WP)
{
    int b = blockIdx.x;
    int t = threadIdx.x;
    if (b < 256) {                           // coarse histogram
        __shared__ int h[NCB];
        for (int i = t; i < NCB; i += 256) h[i] = 0;
        __syncthreads();
        int lo = b * CHUNK, hi = lo + CHUNK;
        for (int e = lo + t; e < hi; e += 256) atomicAdd(&h[ER[e] >> 8], 1);
        __syncthreads();
        for (int i = t; i < NCB; i += 256) ghist[i * 256 + b] = h[i];
        return;
    }
    int bid = b - 256;
    if (bid < 6250) {                        // pad: XPh fp16 (doubles as dense1 X-half)
        int idx = bid * 256 + t;
        int n = idx >> 5;
        int c = idx & 31;
        float v = (c < 30) ? X[n * 30 + c] : 0.f;
        XPh[(size_t)n * 32 + c] = __float2half(v);
    } else if (bid < 6250 + 196) {           // bounds from sorted seg
        int n = (bid - 6250) * 256 + t;
        if (n >= N_NODES) return;
        int g = SEG[n];
        int gprev = (n == 0) ? -1 : SEG[n - 1];
        for (int gg = gprev + 1; gg <= g; ++gg) start[gg] = n;
        if (n == N_NODES - 1)
            for (int gg = g + 1; gg <= N_GRAPHS; ++gg) start[gg] = N_NODES;
    } else {                                 // wpack: 64 x 128
        int idx = (bid - 6446) * 256 + t;
        if (idx >= 64 * 128) return;
        int k = idx >> 7, c = idx & 127;
        float w = 0.f;
        if (k < 30) w = W1[k * 128 + c];
        else if (k >= 32 && k < 62) w = W2[(k - 32) * 128 + c];
        WP[idx] = w;
    }
}

// ---------------------------------------------------------------------------
// scan1: per-bucket exclusive scan of the 256 per-block counts, in place;
// bucket total -> bsum[b].
// ---------------------------------------------------------------------------
__global__ __launch_bounds__(256)
void scan1(int* __restrict__ ghist, int* __restrict__ bsum)
{
    __shared__ int s[256];
    int t = threadIdx.x, b = blockIdx.x;
    int i = b * 256 + t;
    int v = ghist[i];
    s[t] = v;
    __syncthreads();
    for (int off = 1; off < 256; off <<= 1) {
        int u = (t >= off) ? s[t - off] : 0;
        __syncthreads();
        s[t] += u;
        __syncthreads();
    }
    ghist[i] = s[t] - v;
    if (t == 255) bsum[b] = s[255];
}

// ---------------------------------------------------------------------------
// c_scatter: coarse scatter into per-block contiguous runs.
// tmp_sd = src | ((dst&255)<<16) (4B); tmp_w = fp16 weight (2B).
// Runs are sequential within a block -> split arrays still fill whole lines.
// ---------------------------------------------------------------------------
__global__ __launch_bounds__(256)
void c_scatter(const int* __restrict__ ER, const int* __restrict__ EC,
               const float* __restrict__ EW, const int* __restrict__ ghist,
               const int* __restrict__ bsum, unsigned int* __restrict__ tmp_sd,
               __half* __restrict__ tmp_w)
{
    __shared__ int s[256];
    __shared__ int cur[NCB];
    int t = threadIdx.x, blk = blockIdx.x;
    int v = (t < NCB) ? bsum[t] : 0;
    s[t] = v;
    __syncthreads();
    for (int off = 1; off < 256; off <<= 1) {
        int u = (t >= off) ? s[t - off] : 0;
        __syncthreads();
        s[t] += u;
        __syncthreads();
    }
    if (t < NCB) cur[t] = (s[t] - v) + ghist[t * 256 + blk];
    __syncthreads();
    int lo = blk * CHUNK, hi = lo + CHUNK;
    for (int e = lo + t; e < hi; e += 256) {
        int d = ER[e];
        int pos = atomicAdd(&cur[d >> 8], 1);
        tmp_sd[pos] = (unsigned int)EC[e] | ((unsigned int)(d & 255) << 16);
        tmp_w[pos] = __float2half(EW[e]);
    }
}

// ---------------------------------------------------------------------------
// bsort: per-bucket counting sort by dst&255 -> packed 4B records
// (src16 | fp16w<<16) + rowptr.
// ---------------------------------------------------------------------------
__global__ __launch_bounds__(256)
void bsort(const unsigned int* __restrict__ tmp_sd, const __half* __restrict__ tmp_w,
           const int* __restrict__ bsum, unsigned int* __restrict__ packed,
           int* __restrict__ rowptr)
{
    __shared__ int s[256];
    __shared__ int hist[256];
    __shared__ int cur[256];
    int t = threadIdx.x, b = blockIdx.x;
    int v = (t < NCB) ? bsum[t] : 0;
    s[t] = v;
    __syncthreads();
    for (int off = 1; off < 256; off <<= 1) {
        int u = (t >= off) ? s[t - off] : 0;
        __syncthreads();
        s[t] += u;
        __syncthreads();
    }
    int cntb = bsum[b];
    int base = s[b] - cntb;
    int end  = base + cntb;
    __syncthreads();

    hist[t] = 0;
    __syncthreads();
    for (int j = base + t; j < end; j += 256)
        atomicAdd(&hist[(tmp_sd[j] >> 16) & 255], 1);
    __syncthreads();
    int hv = hist[t];
    s[t] = hv;
    __syncthreads();
    for (int off = 1; off < 256; off <<= 1) {
        int u = (t >= off) ? s[t - off] : 0;
        __syncthreads();
        s[t] += u;
        __syncthreads();
    }
    int excl = s[t] - hv;
    int n = b * 256 + t;
    if (n < N_NODES) rowptr[n] = base + excl;
    if (b == NCB - 1 && t == 0) rowptr[N_NODES] = N_EDGES;
    cur[t] = base + excl;
    __syncthreads();
    for (int j = base + t; j < end; j += 256) {
        unsigned int sd = tmp_sd[j];
        unsigned short hb = __half_as_ushort(tmp_w[j]);
        int pos = atomicAdd(&cur[(sd >> 16) & 255], 1);
        packed[pos] = (sd & 0xFFFF) | ((unsigned int)hb << 16);
    }
}

// ---------------------------------------------------------------------------
// Dense GEMM core: lane = row, wave owns 16 cols, B via scalar path.
// ---------------------------------------------------------------------------
template<int K>
__device__ __forceinline__ void gemm16(const float* arow,
                                       const float* __restrict__ Wcol,
                                       int wstride, float acc[16])
{
    #pragma unroll
    for (int j = 0; j < 16; ++j) acc[j] = 0.f;
    for (int k = 0; k < K; k += 4) {
        float4 a = *(const float4*)(arow + k);
        float av[4] = {a.x, a.y, a.z, a.w};
        #pragma unroll
        for (int kk = 0; kk < 4; ++kk) {
            const float* wr = Wcol + (k + kk) * wstride;   // uniform address
            #pragma unroll
            for (int j = 0; j < 16; ++j)
                acc[j] = fmaf(av[kk], wr[j], acc[j]);
        }
    }
}

__device__ __forceinline__ void addbias16(float acc[16],
                                          const float* __restrict__ Bcol)
{
    #pragma unroll
    for (int j4 = 0; j4 < 4; ++j4) {
        float4 bb = *(const float4*)(Bcol + j4 * 4);
        acc[j4*4+0] += bb.x; acc[j4*4+1] += bb.y;
        acc[j4*4+2] += bb.z; acc[j4*4+3] += bb.w;
    }
}

__device__ __forceinline__ void store16h(__half* orow, const float acc[16])
{
    __half2 hb[8];
    #pragma unroll
    for (int j = 0; j < 8; ++j)
        hb[j] = __float22half2_rn(make_float2(acc[2*j], acc[2*j+1]));
    *(uint4*)(orow)     = *(uint4*)&hb[0];
    *(uint4*)(orow + 8) = *(uint4*)&hb[4];
}

// fp16 input staging into fp32 LDS tile (stride K+4), optional relu.
template<int K, int TPB, bool RELU>
__device__ __forceinline__ void stage_Ah(const __half* __restrict__ X,
                                         float* As, int m0)
{
    constexpr int KP = K + 4;
    for (int i = threadIdx.x * 4; i < 64 * K; i += TPB * 4) {
        int row = i / K;
        int col = i % K;
        int gm = m0 + row;
        float4 v = make_float4(0.f, 0.f, 0.f, 0.f);
        if (gm < N_NODES) {
            uint2 raw = *(const uint2*)(X + (size_t)gm * K + col);
            const __half2* hp = (const __half2*)&raw;
            float2 f0 = __half22float2(hp[0]);
            float2 f1 = __half22float2(hp[1]);
            v = make_float4(f0.x, f0.y, f1.x, f1.y);
        }
        if (RELU) {
            v.x = fmaxf(v.x, 0.f); v.y = fmaxf(v.y, 0.f);
            v.z = fmaxf(v.z, 0.f); v.w = fmaxf(v.w, 0.f);
        }
        *(float4*)(As + row * KP + col) = v;
    }
    __syncthreads();
}

// Layer 1: [CIa | XPh] fp16 (N x 64) @ WP (64 x 128) + b -> H1h fp16. 8 waves.
__global__ __launch_bounds__(512)
void dense1_kernel(const __half* __restrict__ CIa, const __half* __restrict__ XPh,
                   const float* __restrict__ WP, const float* __restrict__ Bias,
                   __half* __restrict__ H1h)
{
    __shared__ float As[64 * 68];
    const int m0 = blockIdx.x * 64;
    for (int i = threadIdx.x * 4; i < 64 * 64; i += 512 * 4) {
        int row = i >> 6, col = i & 63;
        int gm = m0 + row;
        float4 v = make_float4(0.f, 0.f, 0.f, 0.f);
        if (gm < N_NODES) {
            const __half* src = (col < 32) ? (CIa + (size_t)gm * 32 + col)
                                           : (XPh + (size_t)gm * 32 + (col - 32));
            uint2 raw = *(const uint2*)src;
            const __half2* hp = (const __half2*)&raw;
            float2 f0 = __half22float2(hp[0]);
            float2 f1 = __half22float2(hp[1]);
            v = make_float4(f0.x, f0.y, f1.x, f1.y);
        }
        *(float4*)(As + row * 68 + col) = v;
    }
    __syncthreads();
    int wid = __builtin_amdgcn_readfirstlane(threadIdx.x >> 6);
    int lane = threadIdx.x & 63;
    float acc[16];
    gemm16<64>(As + lane * 68, WP + wid * 16, 128, acc);
    int gm = m0 + lane;
    if (gm < N_NODES) {
        addbias16(acc, Bias + wid * 16);
        store16h(H1h + (size_t)gm * 128 + wid * 16, acc);
    }
}

// Layer 2: relu(h1h) (N x 128 fp16); waves 0-3 -> W1 -> H2h, 4-7 -> W2 -> A2h (+b).
__global__ __launch_bounds__(512)
void dense2_kernel(const __half* __restrict__ X, const float* __restrict__ W1,
                   const float* __restrict__ W2, const float* __restrict__ Bias,
                   __half* __restrict__ HW1h, __half* __restrict__ AGGh)
{
    __shared__ float As[64 * 132];
    const int m0 = blockIdx.x * 64;
    stage_Ah<128, 512, true>(X, As, m0);
    int wid = __builtin_amdgcn_readfirstlane(threadIdx.x >> 6);
    int lane = threadIdx.x & 63;
    const float* Wc = (wid < 4) ? (W1 + wid * 16) : (W2 + (wid - 4) * 16);
    float acc[16];
    gemm16<128>(As + lane * 132, Wc, 64, acc);
    int gm = m0 + lane;
    if (gm < N_NODES) {
        if (wid < 4)
            store16h(HW1h + (size_t)gm * 64 + wid * 16, acc);
        else {
            addbias16(acc, Bias + (wid - 4) * 16);
            store16h(AGGh + (size_t)gm * 64 + (wid - 4) * 16, acc);
        }
    }
}

// Layer 3: relu(h2h) (N x 64 fp16); waves 0-1 -> W1 -> H3h, 2-3 -> W2 -> B2h (+b).
__global__ __launch_bounds__(256)
void dense3_kernel(const __half* __restrict__ X, const float* __restrict__ W1,
                   const float* __restrict__ W2, const float* __restrict__ Bias,
                   __half* __restrict__ HW1h, __half* __restrict__ AGGh)
{
    __shared__ float As[64 * 68];
    const int m0 = blockIdx.x * 64;
    stage_Ah<64, 256, true>(X, As, m0);
    int wid = __builtin_amdgcn_readfirstlane(threadIdx.x >> 6);
    int lane = threadIdx.x & 63;
    const float* Wc = (wid < 2) ? (W1 + wid * 16) : (W2 + (wid - 2) * 16);
    float acc[16];
    gemm16<64>(As + lane * 68, Wc, 32, acc);
    int gm = m0 + lane;
    if (gm < N_NODES) {
        if (wid < 2)
            store16h(HW1h + (size_t)gm * 32 + wid * 16, acc);
        else {
            addbias16(acc, Bias + (wid - 2) * 16);
            store16h(AGGh + (size_t)gm * 32 + (wid - 2) * 16, acc);
        }
    }
}

// ---------------------------------------------------------------------------
// fp16 gather helpers (unrolled-by-2 edge loops: 2 independent loads/lane in
// flight hides L2 latency).
// ---------------------------------------------------------------------------
__device__ __forceinline__ void fma8h(float4& a0, float4& a1, float w,
                                      const uint4& raw)
{
    const __half2* hp = (const __half2*)&raw;
    float2 f0 = __half22float2(hp[0]);
    float2 f1 = __half22float2(hp[1]);
    float2 f2 = __half22float2(hp[2]);
    float2 f3 = __half22float2(hp[3]);
    a0.x = fmaf(w, f0.x, a0.x); a0.y = fmaf(w, f0.y, a0.y);
    a0.z = fmaf(w, f1.x, a0.z); a0.w = fmaf(w, f1.y, a0.w);
    a1.x = fmaf(w, f2.x, a1.x); a1.y = fmaf(w, f2.y, a1.y);
    a1.z = fmaf(w, f3.x, a1.z); a1.w = fmaf(w, f3.y, a1.w);
}

// aggx_h: CIa[n][0..31] = fp16( sum_j w_j * XPh[src_j][0..31] )
__global__ __launch_bounds__(256)
void aggx_h(const __half* __restrict__ XPh, const int* __restrict__ rowptr,
            const unsigned int* __restrict__ packed, __half* __restrict__ CIa)
{
    int tid = threadIdx.x;
    int local = tid >> 2;
    int q = tid & 3;
    int n = blockIdx.x * 64 + local;
    if (n >= N_NODES) return;
    int r0 = rowptr[n], r1 = rowptr[n + 1];
    float4 acc0 = make_float4(0.f, 0.f, 0.f, 0.f);
    float4 acc1 = make_float4(0.f, 0.f, 0.f, 0.f);
    int j = r0;
    for (; j + 1 < r1; j += 2) {
        unsigned int ra = packed[j], rb = packed[j + 1];
        uint4 rawa = *(const uint4*)(XPh + (size_t)(ra & 0xFFFF) * 32 + q * 8);
        uint4 rawb = *(const uint4*)(XPh + (size_t)(rb & 0xFFFF) * 32 + q * 8);
        float wa = __half2float(__ushort_as_half((unsigned short)(ra >> 16)));
        float wb = __half2float(__ushort_as_half((unsigned short)(rb >> 16)));
        fma8h(acc0, acc1, wa, rawa);
        fma8h(acc0, acc1, wb, rawb);
    }
    if (j < r1) {
        unsigned int r = packed[j];
        uint4 raw = *(const uint4*)(XPh + (size_t)(r & 0xFFFF) * 32 + q * 8);
        float w = __half2float(__ushort_as_half((unsigned short)(r >> 16)));
        fma8h(acc0, acc1, w, raw);
    }
    __half2 hb[4];
    hb[0] = __float22half2_rn(make_float2(acc0.x, acc0.y));
    hb[1] = __float22half2_rn(make_float2(acc0.z, acc0.w));
    hb[2] = __float22half2_rn(make_float2(acc1.x, acc1.y));
    hb[3] = __float22half2_rn(make_float2(acc1.z, acc1.w));
    *(uint4*)(CIa + (size_t)n * 32 + q * 8) = *(uint4*)&hb[0];
}

// spmm_h: fp16 gather rows, fp32 accumulate on top of fp16 AGG (RMW).
template<int FOUT>
__global__ __launch_bounds__(256)
void spmm_h(const __half* __restrict__ H, const int* __restrict__ rowptr,
            const unsigned int* __restrict__ packed, __half* __restrict__ AGGh)
{
    constexpr int T = FOUT / 8;
    int tid = threadIdx.x;
    int local = tid / T;
    int q = tid % T;
    int n = blockIdx.x * (256 / T) + local;
    if (n >= N_NODES) return;
    int r0 = rowptr[n], r1 = rowptr[n + 1];
    __half* ap = AGGh + (size_t)n * FOUT + q * 8;
    float4 acc0, acc1;
    {
        uint4 raw = *(const uint4*)ap;
        const __half2* hp = (const __half2*)&raw;
        float2 f0 = __half22float2(hp[0]);
        float2 f1 = __half22float2(hp[1]);
        float2 f2 = __half22float2(hp[2]);
        float2 f3 = __half22float2(hp[3]);
        acc0 = make_float4(f0.x, f0.y, f1.x, f1.y);
        acc1 = make_float4(f2.x, f2.y, f3.x, f3.y);
    }
    int j = r0;
    for (; j + 1 < r1; j += 2) {
        unsigned int ra = packed[j], rb = packed[j + 1];
        uint4 rawa = *(const uint4*)(H + (size_t)(ra & 0xFFFF) * FOUT + q * 8);
        uint4 rawb = *(const uint4*)(H + (size_t)(rb & 0xFFFF) * FOUT + q * 8);
        float wa = __half2float(__ushort_as_half((unsigned short)(ra >> 16)));
        float wb = __half2float(__ushort_as_half((unsigned short)(rb >> 16)));
        fma8h(acc0, acc1, wa, rawa);
        fma8h(acc0, acc1, wb, rawb);
    }
    if (j < r1) {
        unsigned int r = packed[j];
        uint4 raw = *(const uint4*)(H + (size_t)(r & 0xFFFF) * FOUT + q * 8);
        float w = __half2float(__ushort_as_half((unsigned short)(r >> 16)));
        fma8h(acc0, acc1, w, raw);
    }
    __half2 hb[4];
    hb[0] = __float22half2_rn(make_float2(acc0.x, acc0.y));
    hb[1] = __float22half2_rn(make_float2(acc0.z, acc0.w));
    hb[2] = __float22half2_rn(make_float2(acc1.x, acc1.y));
    hb[3] = __float22half2_rn(make_float2(acc1.z, acc1.w));
    *(uint4*)ap = *(uint4*)&hb[0];
}

// ---------------------------------------------------------------------------
// pool + head fused: one block/graph; mean of relu(h3h fp16), softmax(p@wd+bd).
// ---------------------------------------------------------------------------
__global__ __launch_bounds__(256)
void pool_kernel(const __half* __restrict__ H, const int* __restrict__ start,
                 const float* __restrict__ WD, const float* __restrict__ BD,
                 float* __restrict__ OUT)
{
    __shared__ float red[8][33];
    int g = blockIdx.x;
    int s = start[g], e = start[g + 1];
    int q = threadIdx.x & 31;
    int lane = threadIdx.x >> 5;
    float acc = 0.f;
    for (int n = s + lane; n < e; n += 8)
        acc += fmaxf(__half2float(H[(size_t)n * 32 + q]), 0.f);
    red[lane][q] = acc;
    __syncthreads();
    if (threadIdx.x < 32) {
        float v = 0.f;
        #pragma unroll
        for (int i = 0; i < 8; ++i) v += red[i][q];
        float inv = (e > s) ? 1.0f / (float)(e - s) : 1.0f;
        float p = v * inv;
        float p0 = p * WD[q * 2 + 0];
        float p1 = p * WD[q * 2 + 1];
        #pragma unroll
        for (int off = 16; off; off >>= 1) {
            p0 += __shfl_down(p0, off, 32);
            p1 += __shfl_down(p1, off, 32);
        }
        if (q == 0) {
            float l0 = p0 + BD[0], l1 = p1 + BD[1];
            float m = fmaxf(l0, l1);
            float e0 = expf(l0 - m), e1 = expf(l1 - m);
            float si = 1.0f / (e0 + e1);
            OUT[g * 2 + 0] = e0 * si;
            OUT[g * 2 + 1] = e1 * si;
        }
    }
}

extern "C" void kernel_launch(void* const* d_in, const int* in_sizes, int n_in,
                              void* d_out, int out_size, void* d_ws, size_t ws_size,
                              hipStream_t stream)
{
    const float* x    = (const float*)d_in[0];
    const float* ew   = (const float*)d_in[1];
    const int*   er   = (const int*)d_in[2];
    const int*   ec   = (const int*)d_in[3];
    const int*   seg  = (const int*)d_in[4];
    const float* w1_1 = (const float*)d_in[5];
    const float* w2_1 = (const float*)d_in[6];
    const float* b_1  = (const float*)d_in[7];
    const float* w1_2 = (const float*)d_in[8];
    const float* w2_2 = (const float*)d_in[9];
    const float* b_2  = (const float*)d_in[10];
    const float* w1_3 = (const float*)d_in[11];
    const float* w2_3 = (const float*)d_in[12];
    const float* b_3  = (const float*)d_in[13];
    const float* wd   = (const float*)d_in[14];
    const float* bd   = (const float*)d_in[15];

    float* ws = (float*)d_ws;
    // Phase 1: CIa fp16 at 0 (N x 32), XPh fp16 at 3.2M (N x 32),
    //          H1h fp16 at 6.4M (N x 128); tmp_sd/tmp_w live inside the H1h
    //          region during CSR build (dead before dense1 writes H1h).
    __half* CIa  = (__half*)ws;                  // N x 32 fp16 (A@X half)
    __half* XPh  = (__half*)(ws + 3200000);      // N x 32 fp16 (X half)
    __half* H1h  = (__half*)(ws + 6400000);      // N x 128 fp16 (h1)
    unsigned int* tmp_sd = (unsigned int*)(ws + 6400000);  // E x 4B
    __half* tmp_w = (__half*)(ws + 7200000);     // E x 2B
    // Phase 2: H2h at 0 (CIa dead), A2h at 3.2M (XPh dead)
    __half* H2h  = (__half*)ws;                  // N x 64 fp16
    __half* A2h  = (__half*)(ws + 3200000);      // N x 64 fp16 (h2)
    // Phase 3: H3h at 6.4M (H1h dead), B2h at 8.0M
    __half* H3h  = (__half*)(ws + 6400000);      // N x 32 fp16
    __half* B2h  = (__half*)(ws + 8000000);      // N x 32 fp16 (h3)
    int*    IW   = (int*)d_ws;
    unsigned int* packed = (unsigned int*)(IW + 12800000);  // E x 4B {src16|w16}
    int*    rowptr = IW + 14400000;              // N+1
    int*    ghist  = IW + 14460000;              // NCB*256
    int*    bsum   = IW + 14515000;              // NCB
    int*    start  = IW + 14520000;              // G+1
    float*  WP     = ws + 14540000;              // 64 x 128 packed layer-1 weights

    dim3 blk(256);
    const int MB = (N_NODES + 63) / 64;          // 782

    // ---- CSR build + prep: hist(256)+prep(6478) -> scan -> scatter -> sort ----
    hist_prep<<<dim3(256 + 6478), blk, 0, stream>>>(er, x, seg, w1_1, w2_1,
                                                    ghist, XPh, start, WP);
    scan1<<<dim3(NCB), blk, 0, stream>>>(ghist, bsum);
    c_scatter<<<dim3(256), blk, 0, stream>>>(er, ec, ew, ghist, bsum, tmp_sd, tmp_w);
    bsort<<<dim3(NCB), blk, 0, stream>>>(tmp_sd, tmp_w, bsum, packed, rowptr);

    // Layer 1: CIa = fp16(A@X), h1h = [CIa | XPh] @ WP + b
    aggx_h<<<dim3(MB), blk, 0, stream>>>(XPh, rowptr, packed, CIa);
    dense1_kernel<<<dim3(MB), dim3(512), 0, stream>>>(CIa, XPh, WP, b_1, H1h);
    // Layer 2: relu(h1h)(128) -> 64; both outputs fp16
    dense2_kernel<<<dim3(MB), dim3(512), 0, stream>>>(H1h, w1_2, w2_2, b_2, H2h, A2h);
    spmm_h<64><<<dim3((N_NODES + 31) / 32), blk, 0, stream>>>(H2h, rowptr, packed, A2h);
    // Layer 3: relu(h2h)(64) -> 32; both outputs fp16
    dense3_kernel<<<dim3(MB), blk, 0, stream>>>(A2h, w1_3, w2_3, b_3, H3h, B2h);
    spmm_h<32><<<dim3(MB), blk, 0, stream>>>(H3h, rowptr, packed, B2h);

    // Pool + head (fused, atomic-free)
    pool_kernel<<<dim3(N_GRAPHS), blk, 0, stream>>>(B2h, start, wd, bd, (float*)d_out);
}

// Round 16
// 222.679 us; speedup vs baseline: 1.9279x; 1.0320x over previous
//
#include <hip/hip_runtime.h>
#include <hip/hip_fp16.h>

#define N_NODES 50000
#define N_EDGES 800000
#define N_GRAPHS 256
#define NCB 196        // coarse buckets = ceil(50000/256), dst>>8
#define CHUNK 3125     // edges per block in coarse passes (256 blocks)

// ---------------------------------------------------------------------------
// hist_prep: blocks 0..255 coarse edge histogram (dst>>8); blocks 256..6733
// independent prep (pad XPh, bounds, wpack). Merged: both fully parallel.
// ---------------------------------------------------------------------------
__global__ __launch_bounds__(256)
void hist_prep(const int* __restrict__ ER, const float* __restrict__ X,
               const int* __restrict__ SEG, const float* __restrict__ W1,
               const float* __restrict__ W2, int* __restrict__ ghist,
               __half* __restrict__ XPh, int* __restrict__ start,
               float* __restrict__ WP)
{
    int b = blockIdx.x;
    int t = threadIdx.x;
    if (b < 256) {                           // coarse histogram
        __shared__ int h[NCB];
        for (int i = t; i < NCB; i += 256) h[i] = 0;
        __syncthreads();
        int lo = b * CHUNK, hi = lo + CHUNK;
        for (int e = lo + t; e < hi; e += 256) atomicAdd(&h[ER[e] >> 8], 1);
        __syncthreads();
        for (int i = t; i < NCB; i += 256) ghist[i * 256 + b] = h[i];
        return;
    }
    int bid = b - 256;
    if (bid < 6250) {                        // pad: XPh fp16 (doubles as dense12 X-half)
        int idx = bid * 256 + t;
        int n = idx >> 5;
        int c = idx & 31;
        float v = (c < 30) ? X[n * 30 + c] : 0.f;
        XPh[(size_t)n * 32 + c] = __float2half(v);
    } else if (bid < 6250 + 196) {           // bounds from sorted seg
        int n = (bid - 6250) * 256 + t;
        if (n >= N_NODES) return;
        int g = SEG[n];
        int gprev = (n == 0) ? -1 : SEG[n - 1];
        for (int gg = gprev + 1; gg <= g; ++gg) start[gg] = n;
        if (n == N_NODES - 1)
            for (int gg = g + 1; gg <= N_GRAPHS; ++gg) start[gg] = N_NODES;
    } else {                                 // wpack: 64 x 128
        int idx = (bid - 6446) * 256 + t;
        if (idx >= 64 * 128) return;
        int k = idx >> 7, c = idx & 127;
        float w = 0.f;
        if (k < 30) w = W1[k * 128 + c];
        else if (k >= 32 && k < 62) w = W2[(k - 32) * 128 + c];
        WP[idx] = w;
    }
}

// ---------------------------------------------------------------------------
// scan1: per-bucket exclusive scan of the 256 per-block counts, in place;
// bucket total -> bsum[b].
// ---------------------------------------------------------------------------
__global__ __launch_bounds__(256)
void scan1(int* __restrict__ ghist, int* __restrict__ bsum)
{
    __shared__ int s[256];
    int t = threadIdx.x, b = blockIdx.x;
    int i = b * 256 + t;
    int v = ghist[i];
    s[t] = v;
    __syncthreads();
    for (int off = 1; off < 256; off <<= 1) {
        int u = (t >= off) ? s[t - off] : 0;
        __syncthreads();
        s[t] += u;
        __syncthreads();
    }
    ghist[i] = s[t] - v;
    if (t == 255) bsum[b] = s[255];
}

// ---------------------------------------------------------------------------
// c_scatter: coarse scatter into per-block contiguous runs.
// tmp_sd = src | ((dst&255)<<16) (4B); tmp_w = fp16 weight (2B).
// ---------------------------------------------------------------------------
__global__ __launch_bounds__(256)
void c_scatter(const int* __restrict__ ER, const int* __restrict__ EC,
               const float* __restrict__ EW, const int* __restrict__ ghist,
               const int* __restrict__ bsum, unsigned int* __restrict__ tmp_sd,
               __half* __restrict__ tmp_w)
{
    __shared__ int s[256];
    __shared__ int cur[NCB];
    int t = threadIdx.x, blk = blockIdx.x;
    int v = (t < NCB) ? bsum[t] : 0;
    s[t] = v;
    __syncthreads();
    for (int off = 1; off < 256; off <<= 1) {
        int u = (t >= off) ? s[t - off] : 0;
        __syncthreads();
        s[t] += u;
        __syncthreads();
    }
    if (t < NCB) cur[t] = (s[t] - v) + ghist[t * 256 + blk];
    __syncthreads();
    int lo = blk * CHUNK, hi = lo + CHUNK;
    for (int e = lo + t; e < hi; e += 256) {
        int d = ER[e];
        int pos = atomicAdd(&cur[d >> 8], 1);
        tmp_sd[pos] = (unsigned int)EC[e] | ((unsigned int)(d & 255) << 16);
        tmp_w[pos] = __float2half(EW[e]);
    }
}

// ---------------------------------------------------------------------------
// bsort: per-bucket counting sort by dst&255 -> packed 4B records
// (src16 | fp16w<<16) + rowptr.
// ---------------------------------------------------------------------------
__global__ __launch_bounds__(256)
void bsort(const unsigned int* __restrict__ tmp_sd, const __half* __restrict__ tmp_w,
           const int* __restrict__ bsum, unsigned int* __restrict__ packed,
           int* __restrict__ rowptr)
{
    __shared__ int s[256];
    __shared__ int hist[256];
    __shared__ int cur[256];
    int t = threadIdx.x, b = blockIdx.x;
    int v = (t < NCB) ? bsum[t] : 0;
    s[t] = v;
    __syncthreads();
    for (int off = 1; off < 256; off <<= 1) {
        int u = (t >= off) ? s[t - off] : 0;
        __syncthreads();
        s[t] += u;
        __syncthreads();
    }
    int cntb = bsum[b];
    int base = s[b] - cntb;
    int end  = base + cntb;
    __syncthreads();

    hist[t] = 0;
    __syncthreads();
    for (int j = base + t; j < end; j += 256)
        atomicAdd(&hist[(tmp_sd[j] >> 16) & 255], 1);
    __syncthreads();
    int hv = hist[t];
    s[t] = hv;
    __syncthreads();
    for (int off = 1; off < 256; off <<= 1) {
        int u = (t >= off) ? s[t - off] : 0;
        __syncthreads();
        s[t] += u;
        __syncthreads();
    }
    int excl = s[t] - hv;
    int n = b * 256 + t;
    if (n < N_NODES) rowptr[n] = base + excl;
    if (b == NCB - 1 && t == 0) rowptr[N_NODES] = N_EDGES;
    cur[t] = base + excl;
    __syncthreads();
    for (int j = base + t; j < end; j += 256) {
        unsigned int sd = tmp_sd[j];
        unsigned short hb = __half_as_ushort(tmp_w[j]);
        int pos = atomicAdd(&cur[(sd >> 16) & 255], 1);
        packed[pos] = (sd & 0xFFFF) | ((unsigned int)hb << 16);
    }
}

// ---------------------------------------------------------------------------
// Dense GEMM core: lane = row, wave owns 16 cols, B via scalar path.
// ---------------------------------------------------------------------------
template<int K>
__device__ __forceinline__ void gemm16(const float* arow,
                                       const float* __restrict__ Wcol,
                                       int wstride, float acc[16])
{
    #pragma unroll
    for (int j = 0; j < 16; ++j) acc[j] = 0.f;
    for (int k = 0; k < K; k += 4) {
        float4 a = *(const float4*)(arow + k);
        float av[4] = {a.x, a.y, a.z, a.w};
        #pragma unroll
        for (int kk = 0; kk < 4; ++kk) {
            const float* wr = Wcol + (k + kk) * wstride;   // uniform address
            #pragma unroll
            for (int j = 0; j < 16; ++j)
                acc[j] = fmaf(av[kk], wr[j], acc[j]);
        }
    }
}

__device__ __forceinline__ void addbias16(float acc[16],
                                          const float* __restrict__ Bcol)
{
    #pragma unroll
    for (int j4 = 0; j4 < 4; ++j4) {
        float4 bb = *(const float4*)(Bcol + j4 * 4);
        acc[j4*4+0] += bb.x; acc[j4*4+1] += bb.y;
        acc[j4*4+2] += bb.z; acc[j4*4+3] += bb.w;
    }
}

__device__ __forceinline__ void store16h(__half* orow, const float acc[16])
{
    __half2 hb[8];
    #pragma unroll
    for (int j = 0; j < 8; ++j)
        hb[j] = __float22half2_rn(make_float2(acc[2*j], acc[2*j+1]));
    *(uint4*)(orow)     = *(uint4*)&hb[0];
    *(uint4*)(orow + 8) = *(uint4*)&hb[4];
}

// fp16 input staging into fp32 LDS tile (stride K+4), optional relu.
template<int K, int TPB, bool RELU>
__device__ __forceinline__ void stage_Ah(const __half* __restrict__ X,
                                         float* As, int m0)
{
    constexpr int KP = K + 4;
    for (int i = threadIdx.x * 4; i < 64 * K; i += TPB * 4) {
        int row = i / K;
        int col = i % K;
        int gm = m0 + row;
        float4 v = make_float4(0.f, 0.f, 0.f, 0.f);
        if (gm < N_NODES) {
            uint2 raw = *(const uint2*)(X + (size_t)gm * K + col);
            const __half2* hp = (const __half2*)&raw;
            float2 f0 = __half22float2(hp[0]);
            float2 f1 = __half22float2(hp[1]);
            v = make_float4(f0.x, f0.y, f1.x, f1.y);
        }
        if (RELU) {
            v.x = fmaxf(v.x, 0.f); v.y = fmaxf(v.y, 0.f);
            v.z = fmaxf(v.z, 0.f); v.w = fmaxf(v.w, 0.f);
        }
        *(float4*)(As + row * KP + col) = v;
    }
    __syncthreads();
}

// ---------------------------------------------------------------------------
// dense12: FUSED layers 1+2 (h1 is consumed only by layer 2's dense — never
// materialized). Phase A: [CIa|XPh] @ WP + b1 -> h1 (fp32, registers).
// Phase B: relu(h1) routed through LDS (64 x 132) -> @ [W1_2|W2_2] ->
// H2h fp16 / A2h fp16 (+b2). Saves the 25.6 MB H1h round-trip + 1 dispatch.
// ---------------------------------------------------------------------------
__global__ __launch_bounds__(512)
void dense12_kernel(const __half* __restrict__ CIa, const __half* __restrict__ XPh,
                    const float* __restrict__ WP, const float* __restrict__ B1,
                    const float* __restrict__ W1_2, const float* __restrict__ W2_2,
                    const float* __restrict__ B2, __half* __restrict__ H2h,
                    __half* __restrict__ A2h)
{
    __shared__ float As[64 * 132];
    const int tid = threadIdx.x;
    const int m0 = blockIdx.x * 64;

    // Phase A staging: As[row][0..63] = [CIa | XPh], stride 68
    for (int i = tid * 4; i < 64 * 64; i += 512 * 4) {
        int row = i >> 6, col = i & 63;
        int gm = m0 + row;
        float4 v = make_float4(0.f, 0.f, 0.f, 0.f);
        if (gm < N_NODES) {
            const __half* src = (col < 32) ? (CIa + (size_t)gm * 32 + col)
                                           : (XPh + (size_t)gm * 32 + (col - 32));
            uint2 raw = *(const uint2*)src;
            const __half2* hp = (const __half2*)&raw;
            float2 f0 = __half22float2(hp[0]);
            float2 f1 = __half22float2(hp[1]);
            v = make_float4(f0.x, f0.y, f1.x, f1.y);
        }
        *(float4*)(As + row * 68 + col) = v;
    }
    __syncthreads();

    const int wid = __builtin_amdgcn_readfirstlane(tid >> 6);
    const int lane = tid & 63;

    float acc[16];
    gemm16<64>(As + lane * 68, WP + wid * 16, 128, acc);
    addbias16(acc, B1 + wid * 16);
    #pragma unroll
    for (int j = 0; j < 16; ++j) acc[j] = fmaxf(acc[j], 0.f);

    __syncthreads();                       // all Phase-A reads of As done
    // write relu(h1) tile: As[row=lane][col=wid*16+j], stride 132
    #pragma unroll
    for (int j4 = 0; j4 < 4; ++j4)
        *(float4*)(As + lane * 132 + wid * 16 + j4 * 4) =
            make_float4(acc[j4*4+0], acc[j4*4+1], acc[j4*4+2], acc[j4*4+3]);
    __syncthreads();

    const float* Wc = (wid < 4) ? (W1_2 + wid * 16) : (W2_2 + (wid - 4) * 16);
    float acc2[16];
    gemm16<128>(As + lane * 132, Wc, 64, acc2);
    int gm = m0 + lane;
    if (gm < N_NODES) {
        if (wid < 4)
            store16h(H2h + (size_t)gm * 64 + wid * 16, acc2);
        else {
            addbias16(acc2, B2 + (wid - 4) * 16);
            store16h(A2h + (size_t)gm * 64 + (wid - 4) * 16, acc2);
        }
    }
}

// Layer 3: relu(h2h) (N x 64 fp16); waves 0-1 -> W1 -> H3h, 2-3 -> W2 -> B2h (+b).
__global__ __launch_bounds__(256)
void dense3_kernel(const __half* __restrict__ X, const float* __restrict__ W1,
                   const float* __restrict__ W2, const float* __restrict__ Bias,
                   __half* __restrict__ HW1h, __half* __restrict__ AGGh)
{
    __shared__ float As[64 * 68];
    const int m0 = blockIdx.x * 64;
    stage_Ah<64, 256, true>(X, As, m0);
    int wid = __builtin_amdgcn_readfirstlane(threadIdx.x >> 6);
    int lane = threadIdx.x & 63;
    const float* Wc = (wid < 2) ? (W1 + wid * 16) : (W2 + (wid - 2) * 16);
    float acc[16];
    gemm16<64>(As + lane * 68, Wc, 32, acc);
    int gm = m0 + lane;
    if (gm < N_NODES) {
        if (wid < 2)
            store16h(HW1h + (size_t)gm * 32 + wid * 16, acc);
        else {
            addbias16(acc, Bias + (wid - 2) * 16);
            store16h(AGGh + (size_t)gm * 32 + (wid - 2) * 16, acc);
        }
    }
}

// ---------------------------------------------------------------------------
// fp16 gather helpers (unrolled-by-2 edge loops).
// ---------------------------------------------------------------------------
__device__ __forceinline__ void fma8h(float4& a0, float4& a1, float w,
                                      const uint4& raw)
{
    const __half2* hp = (const __half2*)&raw;
    float2 f0 = __half22float2(hp[0]);
    float2 f1 = __half22float2(hp[1]);
    float2 f2 = __half22float2(hp[2]);
    float2 f3 = __half22float2(hp[3]);
    a0.x = fmaf(w, f0.x, a0.x); a0.y = fmaf(w, f0.y, a0.y);
    a0.z = fmaf(w, f1.x, a0.z); a0.w = fmaf(w, f1.y, a0.w);
    a1.x = fmaf(w, f2.x, a1.x); a1.y = fmaf(w, f2.y, a1.y);
    a1.z = fmaf(w, f3.x, a1.z); a1.w = fmaf(w, f3.y, a1.w);
}

// aggx_h: CIa[n][0..31] = fp16( sum_j w_j * XPh[src_j][0..31] )
__global__ __launch_bounds__(256)
void aggx_h(const __half* __restrict__ XPh, const int* __restrict__ rowptr,
            const unsigned int* __restrict__ packed, __half* __restrict__ CIa)
{
    int tid = threadIdx.x;
    int local = tid >> 2;
    int q = tid & 3;
    int n = blockIdx.x * 64 + local;
    if (n >= N_NODES) return;
    int r0 = rowptr[n], r1 = rowptr[n + 1];
    float4 acc0 = make_float4(0.f, 0.f, 0.f, 0.f);
    float4 acc1 = make_float4(0.f, 0.f, 0.f, 0.f);
    int j = r0;
    for (; j + 1 < r1; j += 2) {
        unsigned int ra = packed[j], rb = packed[j + 1];
        uint4 rawa = *(const uint4*)(XPh + (size_t)(ra & 0xFFFF) * 32 + q * 8);
        uint4 rawb = *(const uint4*)(XPh + (size_t)(rb & 0xFFFF) * 32 + q * 8);
        float wa = __half2float(__ushort_as_half((unsigned short)(ra >> 16)));
        float wb = __half2float(__ushort_as_half((unsigned short)(rb >> 16)));
        fma8h(acc0, acc1, wa, rawa);
        fma8h(acc0, acc1, wb, rawb);
    }
    if (j < r1) {
        unsigned int r = packed[j];
        uint4 raw = *(const uint4*)(XPh + (size_t)(r & 0xFFFF) * 32 + q * 8);
        float w = __half2float(__ushort_as_half((unsigned short)(r >> 16)));
        fma8h(acc0, acc1, w, raw);
    }
    __half2 hb[4];
    hb[0] = __float22half2_rn(make_float2(acc0.x, acc0.y));
    hb[1] = __float22half2_rn(make_float2(acc0.z, acc0.w));
    hb[2] = __float22half2_rn(make_float2(acc1.x, acc1.y));
    hb[3] = __float22half2_rn(make_float2(acc1.z, acc1.w));
    *(uint4*)(CIa + (size_t)n * 32 + q * 8) = *(uint4*)&hb[0];
}

// spmm_h: fp16 gather rows, fp32 accumulate on top of fp16 AGG (RMW).
template<int FOUT>
__global__ __launch_bounds__(256)
void spmm_h(const __half* __restrict__ H, const int* __restrict__ rowptr,
            const unsigned int* __restrict__ packed, __half* __restrict__ AGGh)
{
    constexpr int T = FOUT / 8;
    int tid = threadIdx.x;
    int local = tid / T;
    int q = tid % T;
    int n = blockIdx.x * (256 / T) + local;
    if (n >= N_NODES) return;
    int r0 = rowptr[n], r1 = rowptr[n + 1];
    __half* ap = AGGh + (size_t)n * FOUT + q * 8;
    float4 acc0, acc1;
    {
        uint4 raw = *(const uint4*)ap;
        const __half2* hp = (const __half2*)&raw;
        float2 f0 = __half22float2(hp[0]);
        float2 f1 = __half22float2(hp[1]);
        float2 f2 = __half22float2(hp[2]);
        float2 f3 = __half22float2(hp[3]);
        acc0 = make_float4(f0.x, f0.y, f1.x, f1.y);
        acc1 = make_float4(f2.x, f2.y, f3.x, f3.y);
    }
    int j = r0;
    for (; j + 1 < r1; j += 2) {
        unsigned int ra = packed[j], rb = packed[j + 1];
        uint4 rawa = *(const uint4*)(H + (size_t)(ra & 0xFFFF) * FOUT + q * 8);
        uint4 rawb = *(const uint4*)(H + (size_t)(rb & 0xFFFF) * FOUT + q * 8);
        float wa = __half2float(__ushort_as_half((unsigned short)(ra >> 16)));
        float wb = __half2float(__ushort_as_half((unsigned short)(rb >> 16)));
        fma8h(acc0, acc1, wa, rawa);
        fma8h(acc0, acc1, wb, rawb);
    }
    if (j < r1) {
        unsigned int r = packed[j];
        uint4 raw = *(const uint4*)(H + (size_t)(r & 0xFFFF) * FOUT + q * 8);
        float w = __half2float(__ushort_as_half((unsigned short)(r >> 16)));
        fma8h(acc0, acc1, w, raw);
    }
    __half2 hb[4];
    hb[0] = __float22half2_rn(make_float2(acc0.x, acc0.y));
    hb[1] = __float22half2_rn(make_float2(acc0.z, acc0.w));
    hb[2] = __float22half2_rn(make_float2(acc1.x, acc1.y));
    hb[3] = __float22half2_rn(make_float2(acc1.z, acc1.w));
    *(uint4*)ap = *(uint4*)&hb[0];
}

// ---------------------------------------------------------------------------
// pool + head fused: one block/graph; mean of relu(h3h fp16), softmax(p@wd+bd).
// ---------------------------------------------------------------------------
__global__ __launch_bounds__(256)
void pool_kernel(const __half* __restrict__ H, const int* __restrict__ start,
                 const float* __restrict__ WD, const float* __restrict__ BD,
                 float* __restrict__ OUT)
{
    __shared__ float red[8][33];
    int g = blockIdx.x;
    int s = start[g], e = start[g + 1];
    int q = threadIdx.x & 31;
    int lane = threadIdx.x >> 5;
    float acc = 0.f;
    for (int n = s + lane; n < e; n += 8)
        acc += fmaxf(__half2float(H[(size_t)n * 32 + q]), 0.f);
    red[lane][q] = acc;
    __syncthreads();
    if (threadIdx.x < 32) {
        float v = 0.f;
        #pragma unroll
        for (int i = 0; i < 8; ++i) v += red[i][q];
        float inv = (e > s) ? 1.0f / (float)(e - s) : 1.0f;
        float p = v * inv;
        float p0 = p * WD[q * 2 + 0];
        float p1 = p * WD[q * 2 + 1];
        #pragma unroll
        for (int off = 16; off; off >>= 1) {
            p0 += __shfl_down(p0, off, 32);
            p1 += __shfl_down(p1, off, 32);
        }
        if (q == 0) {
            float l0 = p0 + BD[0], l1 = p1 + BD[1];
            float m = fmaxf(l0, l1);
            float e0 = expf(l0 - m), e1 = expf(l1 - m);
            float si = 1.0f / (e0 + e1);
            OUT[g * 2 + 0] = e0 * si;
            OUT[g * 2 + 1] = e1 * si;
        }
    }
}

extern "C" void kernel_launch(void* const* d_in, const int* in_sizes, int n_in,
                              void* d_out, int out_size, void* d_ws, size_t ws_size,
                              hipStream_t stream)
{
    const float* x    = (const float*)d_in[0];
    const float* ew   = (const float*)d_in[1];
    const int*   er   = (const int*)d_in[2];
    const int*   ec   = (const int*)d_in[3];
    const int*   seg  = (const int*)d_in[4];
    const float* w1_1 = (const float*)d_in[5];
    const float* w2_1 = (const float*)d_in[6];
    const float* b_1  = (const float*)d_in[7];
    const float* w1_2 = (const float*)d_in[8];
    const float* w2_2 = (const float*)d_in[9];
    const float* b_2  = (const float*)d_in[10];
    const float* w1_3 = (const float*)d_in[11];
    const float* w2_3 = (const float*)d_in[12];
    const float* b_3  = (const float*)d_in[13];
    const float* wd   = (const float*)d_in[14];
    const float* bd   = (const float*)d_in[15];

    float* ws = (float*)d_ws;
    int*   IW = (int*)d_ws;
    // Fully disjoint workspace (ws_size >> 40 MB) — no aliasing hazards.
    __half* XPh    = (__half*)ws;                   // N x 32 fp16   [0, 3.2M)
    __half* CIa    = (__half*)(ws + 800000);        // N x 32 fp16   [3.2M, 6.4M)
    unsigned int* tmp_sd = (unsigned int*)(ws + 1600000);  // E x 4B [6.4M, 9.6M)
    __half* tmp_w  = (__half*)(ws + 2400000);       // E x 2B        [9.6M, 11.2M)
    __half* H2h    = (__half*)(ws + 3200000);       // N x 64 fp16   [12.8M, 19.2M)
    __half* A2h    = (__half*)(ws + 4800000);       // N x 64 fp16   [19.2M, 25.6M)
    __half* H3h    = (__half*)(ws + 6400000);       // N x 32 fp16   [25.6M, 28.8M)
    __half* B2h    = (__half*)(ws + 7200000);       // N x 32 fp16   [28.8M, 32M)
    unsigned int* packed = (unsigned int*)(IW + 8000000);  // E x 4B [32M, 35.2M)
    int*    rowptr = IW + 9000000;                  // N+1
    int*    ghist  = IW + 9060000;                  // NCB*256
    int*    bsum   = IW + 9115000;                  // NCB
    int*    start  = IW + 9120000;                  // G+1
    float*  WP     = ws + 9125000;                  // 64 x 128 packed layer-1 W

    dim3 blk(256);
    const int MB = (N_NODES + 63) / 64;             // 782

    // ---- CSR build + prep: hist(256)+prep(6478) -> scan -> scatter -> sort ----
    hist_prep<<<dim3(256 + 6478), blk, 0, stream>>>(er, x, seg, w1_1, w2_1,
                                                    ghist, XPh, start, WP);
    scan1<<<dim3(NCB), blk, 0, stream>>>(ghist, bsum);
    c_scatter<<<dim3(256), blk, 0, stream>>>(er, ec, ew, ghist, bsum, tmp_sd, tmp_w);
    bsort<<<dim3(NCB), blk, 0, stream>>>(tmp_sd, tmp_w, bsum, packed, rowptr);

    // Layers 1+2 fused: CIa = fp16(A@X); [CIa|XPh] @ WP + b1 -> relu -> @[W1_2|W2_2]
    aggx_h<<<dim3(MB), blk, 0, stream>>>(XPh, rowptr, packed, CIa);
    dense12_kernel<<<dim3(MB), dim3(512), 0, stream>>>(CIa, XPh, WP, b_1,
                                                       w1_2, w2_2, b_2, H2h, A2h);
    spmm_h<64><<<dim3((N_NODES + 31) / 32), blk, 0, stream>>>(H2h, rowptr, packed, A2h);
    // Layer 3: relu(h2h)(64) -> 32; both outputs fp16
    dense3_kernel<<<dim3(MB), blk, 0, stream>>>(A2h, w1_3, w2_3, b_3, H3h, B2h);
    spmm_h<32><<<dim3(MB), blk, 0, stream>>>(H3h, rowptr, packed, B2h);

    // Pool + head (fused, atomic-free)
    pool_kernel<<<dim3(N_GRAPHS), blk, 0, stream>>>(B2h, start, wd, bd, (float*)d_out);
}

// Round 17
// 217.708 us; speedup vs baseline: 1.9719x; 1.0228x over previous
//
#include <hip/hip_runtime.h>
#include <hip/hip_fp16.h>

#define N_NODES 50000
#define N_EDGES 800000
#define N_GRAPHS 256
#define NCB 196        // coarse buckets = ceil(50000/256), dst>>8
#define CHUNK 3125     // edges per block in coarse passes (256 blocks)

// ---------------------------------------------------------------------------
// hist_prep: blocks 0..255 coarse edge histogram (dst>>8); blocks 256..6733
// independent prep (pad XPh, bounds, wpack). Merged: both fully parallel.
// ---------------------------------------------------------------------------
__global__ __launch_bounds__(256)
void hist_prep(const int* __restrict__ ER, const float* __restrict__ X,
               const int* __restrict__ SEG, const float* __restrict__ W1,
               const float* __restrict__ W2, int* __restrict__ ghist,
               __half* __restrict__ XPh, int* __restrict__ start,
               float* __restrict__ WP)
{
    int b = blockIdx.x;
    int t = threadIdx.x;
    if (b < 256) {                           // coarse histogram
        __shared__ int h[NCB];
        for (int i = t; i < NCB; i += 256) h[i] = 0;
        __syncthreads();
        int lo = b * CHUNK, hi = lo + CHUNK;
        for (int e = lo + t; e < hi; e += 256) atomicAdd(&h[ER[e] >> 8], 1);
        __syncthreads();
        for (int i = t; i < NCB; i += 256) ghist[i * 256 + b] = h[i];
        return;
    }
    int bid = b - 256;
    if (bid < 6250) {                        // pad: XPh fp16 (doubles as dense12 X-half)
        int idx = bid * 256 + t;
        int n = idx >> 5;
        int c = idx & 31;
        float v = (c < 30) ? X[n * 30 + c] : 0.f;
        XPh[(size_t)n * 32 + c] = __float2half(v);
    } else if (bid < 6250 + 196) {           // bounds from sorted seg
        int n = (bid - 6250) * 256 + t;
        if (n >= N_NODES) return;
        int g = SEG[n];
        int gprev = (n == 0) ? -1 : SEG[n - 1];
        for (int gg = gprev + 1; gg <= g; ++gg) start[gg] = n;
        if (n == N_NODES - 1)
            for (int gg = g + 1; gg <= N_GRAPHS; ++gg) start[gg] = N_NODES;
    } else {                                 // wpack: 64 x 128
        int idx = (bid - 6446) * 256 + t;
        if (idx >= 64 * 128) return;
        int k = idx >> 7, c = idx & 127;
        float w = 0.f;
        if (k < 30) w = W1[k * 128 + c];
        else if (k >= 32 && k < 62) w = W2[(k - 32) * 128 + c];
        WP[idx] = w;
    }
}

// ---------------------------------------------------------------------------
// scan1: per-bucket exclusive scan of the 256 per-block counts, in place;
// bucket total -> bsum[b].
// ---------------------------------------------------------------------------
__global__ __launch_bounds__(256)
void scan1(int* __restrict__ ghist, int* __restrict__ bsum)
{
    __shared__ int s[256];
    int t = threadIdx.x, b = blockIdx.x;
    int i = b * 256 + t;
    int v = ghist[i];
    s[t] = v;
    __syncthreads();
    for (int off = 1; off < 256; off <<= 1) {
        int u = (t >= off) ? s[t - off] : 0;
        __syncthreads();
        s[t] += u;
        __syncthreads();
    }
    ghist[i] = s[t] - v;
    if (t == 255) bsum[b] = s[255];
}

// ---------------------------------------------------------------------------
// c_scatter: coarse scatter into per-block contiguous runs.
// tmp_sd = src | ((dst&255)<<16) (4B); tmp_w = fp16 weight (2B).
// ---------------------------------------------------------------------------
__global__ __launch_bounds__(256)
void c_scatter(const int* __restrict__ ER, const int* __restrict__ EC,
               const float* __restrict__ EW, const int* __restrict__ ghist,
               const int* __restrict__ bsum, unsigned int* __restrict__ tmp_sd,
               __half* __restrict__ tmp_w)
{
    __shared__ int s[256];
    __shared__ int cur[NCB];
    int t = threadIdx.x, blk = blockIdx.x;
    int v = (t < NCB) ? bsum[t] : 0;
    s[t] = v;
    __syncthreads();
    for (int off = 1; off < 256; off <<= 1) {
        int u = (t >= off) ? s[t - off] : 0;
        __syncthreads();
        s[t] += u;
        __syncthreads();
    }
    if (t < NCB) cur[t] = (s[t] - v) + ghist[t * 256 + blk];
    __syncthreads();
    int lo = blk * CHUNK, hi = lo + CHUNK;
    for (int e = lo + t; e < hi; e += 256) {
        int d = ER[e];
        int pos = atomicAdd(&cur[d >> 8], 1);
        tmp_sd[pos] = (unsigned int)EC[e] | ((unsigned int)(d & 255) << 16);
        tmp_w[pos] = __float2half(EW[e]);
    }
}

// ---------------------------------------------------------------------------
// fp16 gather helper
// ---------------------------------------------------------------------------
__device__ __forceinline__ void fma8h(float4& a0, float4& a1, float w,
                                      const uint4& raw)
{
    const __half2* hp = (const __half2*)&raw;
    float2 f0 = __half22float2(hp[0]);
    float2 f1 = __half22float2(hp[1]);
    float2 f2 = __half22float2(hp[2]);
    float2 f3 = __half22float2(hp[3]);
    a0.x = fmaf(w, f0.x, a0.x); a0.y = fmaf(w, f0.y, a0.y);
    a0.z = fmaf(w, f1.x, a0.z); a0.w = fmaf(w, f1.y, a0.w);
    a1.x = fmaf(w, f2.x, a1.x); a1.y = fmaf(w, f2.y, a1.y);
    a1.z = fmaf(w, f3.x, a1.z); a1.w = fmaf(w, f3.y, a1.w);
}

// ---------------------------------------------------------------------------
// bsort_aggx (512 thr): per-bucket counting sort by dst&255 -> packed 4B
// records + rowptr, THEN the same block does layer-1 aggx for its own 256
// nodes (their CSR runs are entirely this block's output — exact per-block
// dependency, packed still L1/L2-hot). Saves one dispatch.
// ---------------------------------------------------------------------------
__global__ __launch_bounds__(512)
void bsort_aggx(const unsigned int* __restrict__ tmp_sd, const __half* __restrict__ tmp_w,
                const int* __restrict__ bsum, const __half* __restrict__ XPh,
                unsigned int* __restrict__ packed, int* __restrict__ rowptr,
                __half* __restrict__ CIa)
{
    __shared__ int s[256];
    __shared__ int hist[256];
    __shared__ int cur[256];
    __shared__ int r0arr[257];
    int t = threadIdx.x, b = blockIdx.x;

    // bucket base via local scan of bsum (threads 0..255 active in scans)
    if (t < 256) s[t] = (t < NCB) ? bsum[t] : 0;
    __syncthreads();
    for (int off = 1; off < 256; off <<= 1) {
        int u = 0;
        if (t < 256 && t >= off) u = s[t - off];
        __syncthreads();
        if (t < 256) s[t] += u;
        __syncthreads();
    }
    int cntb = bsum[b];
    int base = s[b] - cntb;
    int end  = base + cntb;
    __syncthreads();

    if (t < 256) hist[t] = 0;
    __syncthreads();
    for (int j = base + t; j < end; j += 512)
        atomicAdd(&hist[(tmp_sd[j] >> 16) & 255], 1);
    __syncthreads();
    int hv = 0;
    if (t < 256) { hv = hist[t]; s[t] = hv; }
    __syncthreads();
    for (int off = 1; off < 256; off <<= 1) {
        int u = 0;
        if (t < 256 && t >= off) u = s[t - off];
        __syncthreads();
        if (t < 256) s[t] += u;
        __syncthreads();
    }
    if (t < 256) {
        int excl = s[t] - hv;
        int n = b * 256 + t;
        if (n < N_NODES) rowptr[n] = base + excl;
        if (b == NCB - 1 && t == 0) rowptr[N_NODES] = N_EDGES;
        r0arr[t] = base + excl;
        cur[t] = base + excl;
        if (t == 0) r0arr[256] = end;
    }
    __syncthreads();
    for (int j = base + t; j < end; j += 512) {
        unsigned int sd = tmp_sd[j];
        unsigned short hb = __half_as_ushort(tmp_w[j]);
        int pos = atomicAdd(&cur[(sd >> 16) & 255], 1);
        packed[pos] = (sd & 0xFFFF) | ((unsigned int)hb << 16);
    }
    __syncthreads();   // packed writes drained (vmcnt before barrier)

    // aggx: 4 lanes/node, 128 nodes/pass, 2 passes over the bucket's nodes.
    #pragma unroll
    for (int pass = 0; pass < 2; ++pass) {
        int local = pass * 128 + (t >> 2);
        int q = t & 3;
        int n = b * 256 + local;
        if (n < N_NODES) {
            int r0 = r0arr[local], r1 = r0arr[local + 1];
            float4 acc0 = make_float4(0.f, 0.f, 0.f, 0.f);
            float4 acc1 = make_float4(0.f, 0.f, 0.f, 0.f);
            int j = r0;
            for (; j + 1 < r1; j += 2) {
                unsigned int ra = packed[j], rb = packed[j + 1];
                uint4 rawa = *(const uint4*)(XPh + (size_t)(ra & 0xFFFF) * 32 + q * 8);
                uint4 rawb = *(const uint4*)(XPh + (size_t)(rb & 0xFFFF) * 32 + q * 8);
                float wa = __half2float(__ushort_as_half((unsigned short)(ra >> 16)));
                float wb = __half2float(__ushort_as_half((unsigned short)(rb >> 16)));
                fma8h(acc0, acc1, wa, rawa);
                fma8h(acc0, acc1, wb, rawb);
            }
            if (j < r1) {
                unsigned int r = packed[j];
                uint4 raw = *(const uint4*)(XPh + (size_t)(r & 0xFFFF) * 32 + q * 8);
                float w = __half2float(__ushort_as_half((unsigned short)(r >> 16)));
                fma8h(acc0, acc1, w, raw);
            }
            __half2 hb2[4];
            hb2[0] = __float22half2_rn(make_float2(acc0.x, acc0.y));
            hb2[1] = __float22half2_rn(make_float2(acc0.z, acc0.w));
            hb2[2] = __float22half2_rn(make_float2(acc1.x, acc1.y));
            hb2[3] = __float22half2_rn(make_float2(acc1.z, acc1.w));
            *(uint4*)(CIa + (size_t)n * 32 + q * 8) = *(uint4*)&hb2[0];
        }
    }
}

// ---------------------------------------------------------------------------
// Dense GEMM core: lane = row, wave owns 16 cols, B via scalar path.
// ---------------------------------------------------------------------------
template<int K>
__device__ __forceinline__ void gemm16(const float* arow,
                                       const float* __restrict__ Wcol,
                                       int wstride, float acc[16])
{
    #pragma unroll
    for (int j = 0; j < 16; ++j) acc[j] = 0.f;
    for (int k = 0; k < K; k += 4) {
        float4 a = *(const float4*)(arow + k);
        float av[4] = {a.x, a.y, a.z, a.w};
        #pragma unroll
        for (int kk = 0; kk < 4; ++kk) {
            const float* wr = Wcol + (k + kk) * wstride;   // uniform address
            #pragma unroll
            for (int j = 0; j < 16; ++j)
                acc[j] = fmaf(av[kk], wr[j], acc[j]);
        }
    }
}

__device__ __forceinline__ void addbias16(float acc[16],
                                          const float* __restrict__ Bcol)
{
    #pragma unroll
    for (int j4 = 0; j4 < 4; ++j4) {
        float4 bb = *(const float4*)(Bcol + j4 * 4);
        acc[j4*4+0] += bb.x; acc[j4*4+1] += bb.y;
        acc[j4*4+2] += bb.z; acc[j4*4+3] += bb.w;
    }
}

__device__ __forceinline__ void store16h(__half* orow, const float acc[16])
{
    __half2 hb[8];
    #pragma unroll
    for (int j = 0; j < 8; ++j)
        hb[j] = __float22half2_rn(make_float2(acc[2*j], acc[2*j+1]));
    *(uint4*)(orow)     = *(uint4*)&hb[0];
    *(uint4*)(orow + 8) = *(uint4*)&hb[4];
}

// fp16 input staging into fp32 LDS tile (stride K+4), optional relu.
template<int K, int TPB, bool RELU>
__device__ __forceinline__ void stage_Ah(const __half* __restrict__ X,
                                         float* As, int m0)
{
    constexpr int KP = K + 4;
    for (int i = threadIdx.x * 4; i < 64 * K; i += TPB * 4) {
        int row = i / K;
        int col = i % K;
        int gm = m0 + row;
        float4 v = make_float4(0.f, 0.f, 0.f, 0.f);
        if (gm < N_NODES) {
            uint2 raw = *(const uint2*)(X + (size_t)gm * K + col);
            const __half2* hp = (const __half2*)&raw;
            float2 f0 = __half22float2(hp[0]);
            float2 f1 = __half22float2(hp[1]);
            v = make_float4(f0.x, f0.y, f1.x, f1.y);
        }
        if (RELU) {
            v.x = fmaxf(v.x, 0.f); v.y = fmaxf(v.y, 0.f);
            v.z = fmaxf(v.z, 0.f); v.w = fmaxf(v.w, 0.f);
        }
        *(float4*)(As + row * KP + col) = v;
    }
    __syncthreads();
}

// ---------------------------------------------------------------------------
// dense12: FUSED layers 1+2. Phase A: [CIa|XPh] @ WP + b1 -> h1 (fp32 regs).
// Phase B: relu(h1) via LDS -> @ [W1_2|W2_2] -> H2h / A2h (+b2).
// ---------------------------------------------------------------------------
__global__ __launch_bounds__(512)
void dense12_kernel(const __half* __restrict__ CIa, const __half* __restrict__ XPh,
                    const float* __restrict__ WP, const float* __restrict__ B1,
                    const float* __restrict__ W1_2, const float* __restrict__ W2_2,
                    const float* __restrict__ B2, __half* __restrict__ H2h,
                    __half* __restrict__ A2h)
{
    __shared__ float As[64 * 132];
    const int tid = threadIdx.x;
    const int m0 = blockIdx.x * 64;

    for (int i = tid * 4; i < 64 * 64; i += 512 * 4) {
        int row = i >> 6, col = i & 63;
        int gm = m0 + row;
        float4 v = make_float4(0.f, 0.f, 0.f, 0.f);
        if (gm < N_NODES) {
            const __half* src = (col < 32) ? (CIa + (size_t)gm * 32 + col)
                                           : (XPh + (size_t)gm * 32 + (col - 32));
            uint2 raw = *(const uint2*)src;
            const __half2* hp = (const __half2*)&raw;
            float2 f0 = __half22float2(hp[0]);
            float2 f1 = __half22float2(hp[1]);
            v = make_float4(f0.x, f0.y, f1.x, f1.y);
        }
        *(float4*)(As + row * 68 + col) = v;
    }
    __syncthreads();

    const int wid = __builtin_amdgcn_readfirstlane(tid >> 6);
    const int lane = tid & 63;

    float acc[16];
    gemm16<64>(As + lane * 68, WP + wid * 16, 128, acc);
    addbias16(acc, B1 + wid * 16);
    #pragma unroll
    for (int j = 0; j < 16; ++j) acc[j] = fmaxf(acc[j], 0.f);

    __syncthreads();
    #pragma unroll
    for (int j4 = 0; j4 < 4; ++j4)
        *(float4*)(As + lane * 132 + wid * 16 + j4 * 4) =
            make_float4(acc[j4*4+0], acc[j4*4+1], acc[j4*4+2], acc[j4*4+3]);
    __syncthreads();

    const float* Wc = (wid < 4) ? (W1_2 + wid * 16) : (W2_2 + (wid - 4) * 16);
    float acc2[16];
    gemm16<128>(As + lane * 132, Wc, 64, acc2);
    int gm = m0 + lane;
    if (gm < N_NODES) {
        if (wid < 4)
            store16h(H2h + (size_t)gm * 64 + wid * 16, acc2);
        else {
            addbias16(acc2, B2 + (wid - 4) * 16);
            store16h(A2h + (size_t)gm * 64 + (wid - 4) * 16, acc2);
        }
    }
}

// Layer 3: relu(h2h) (N x 64 fp16); waves 0-1 -> W1 -> H3h, 2-3 -> W2 -> B2h (+b).
__global__ __launch_bounds__(256)
void dense3_kernel(const __half* __restrict__ X, const float* __restrict__ W1,
                   const float* __restrict__ W2, const float* __restrict__ Bias,
                   __half* __restrict__ HW1h, __half* __restrict__ AGGh)
{
    __shared__ float As[64 * 68];
    const int m0 = blockIdx.x * 64;
    stage_Ah<64, 256, true>(X, As, m0);
    int wid = __builtin_amdgcn_readfirstlane(threadIdx.x >> 6);
    int lane = threadIdx.x & 63;
    const float* Wc = (wid < 2) ? (W1 + wid * 16) : (W2 + (wid - 2) * 16);
    float acc[16];
    gemm16<64>(As + lane * 68, Wc, 32, acc);
    int gm = m0 + lane;
    if (gm < N_NODES) {
        if (wid < 2)
            store16h(HW1h + (size_t)gm * 32 + wid * 16, acc);
        else {
            addbias16(acc, Bias + (wid - 2) * 16);
            store16h(AGGh + (size_t)gm * 32 + (wid - 2) * 16, acc);
        }
    }
}

// ---------------------------------------------------------------------------
// spmm_h: fp16 gather rows, fp32 accumulate on top of fp16 AGG (RMW).
// Unrolled by 4: 4 independent 16B loads in flight per lane.
// ---------------------------------------------------------------------------
template<int FOUT>
__global__ __launch_bounds__(256)
void spmm_h(const __half* __restrict__ H, const int* __restrict__ rowptr,
            const unsigned int* __restrict__ packed, __half* __restrict__ AGGh)
{
    constexpr int T = FOUT / 8;
    int tid = threadIdx.x;
    int local = tid / T;
    int q = tid % T;
    int n = blockIdx.x * (256 / T) + local;
    if (n >= N_NODES) return;
    int r0 = rowptr[n], r1 = rowptr[n + 1];
    __half* ap = AGGh + (size_t)n * FOUT + q * 8;
    float4 acc0, acc1;
    {
        uint4 raw = *(const uint4*)ap;
        const __half2* hp = (const __half2*)&raw;
        float2 f0 = __half22float2(hp[0]);
        float2 f1 = __half22float2(hp[1]);
        float2 f2 = __half22float2(hp[2]);
        float2 f3 = __half22float2(hp[3]);
        acc0 = make_float4(f0.x, f0.y, f1.x, f1.y);
        acc1 = make_float4(f2.x, f2.y, f3.x, f3.y);
    }
    int j = r0;
    for (; j + 3 < r1; j += 4) {
        unsigned int ra = packed[j],     rb = packed[j + 1];
        unsigned int rc = packed[j + 2], rd = packed[j + 3];
        uint4 rawa = *(const uint4*)(H + (size_t)(ra & 0xFFFF) * FOUT + q * 8);
        uint4 rawb = *(const uint4*)(H + (size_t)(rb & 0xFFFF) * FOUT + q * 8);
        uint4 rawc = *(const uint4*)(H + (size_t)(rc & 0xFFFF) * FOUT + q * 8);
        uint4 rawd = *(const uint4*)(H + (size_t)(rd & 0xFFFF) * FOUT + q * 8);
        float wa = __half2float(__ushort_as_half((unsigned short)(ra >> 16)));
        float wb = __half2float(__ushort_as_half((unsigned short)(rb >> 16)));
        float wc = __half2float(__ushort_as_half((unsigned short)(rc >> 16)));
        float wd = __half2float(__ushort_as_half((unsigned short)(rd >> 16)));
        fma8h(acc0, acc1, wa, rawa);
        fma8h(acc0, acc1, wb, rawb);
        fma8h(acc0, acc1, wc, rawc);
        fma8h(acc0, acc1, wd, rawd);
    }
    for (; j < r1; ++j) {
        unsigned int r = packed[j];
        uint4 raw = *(const uint4*)(H + (size_t)(r & 0xFFFF) * FOUT + q * 8);
        float w = __half2float(__ushort_as_half((unsigned short)(r >> 16)));
        fma8h(acc0, acc1, w, raw);
    }
    __half2 hb[4];
    hb[0] = __float22half2_rn(make_float2(acc0.x, acc0.y));
    hb[1] = __float22half2_rn(make_float2(acc0.z, acc0.w));
    hb[2] = __float22half2_rn(make_float2(acc1.x, acc1.y));
    hb[3] = __float22half2_rn(make_float2(acc1.z, acc1.w));
    *(uint4*)ap = *(uint4*)&hb[0];
}

// ---------------------------------------------------------------------------
// pool + head fused: one block/graph; mean of relu(h3h fp16), softmax(p@wd+bd).
// ---------------------------------------------------------------------------
__global__ __launch_bounds__(256)
void pool_kernel(const __half* __restrict__ H, const int* __restrict__ start,
                 const float* __restrict__ WD, const float* __restrict__ BD,
                 float* __restrict__ OUT)
{
    __shared__ float red[8][33];
    int g = blockIdx.x;
    int s = start[g], e = start[g + 1];
    int q = threadIdx.x & 31;
    int lane = threadIdx.x >> 5;
    float acc = 0.f;
    for (int n = s + lane; n < e; n += 8)
        acc += fmaxf(__half2float(H[(size_t)n * 32 + q]), 0.f);
    red[lane][q] = acc;
    __syncthreads();
    if (threadIdx.x < 32) {
        float v = 0.f;
        #pragma unroll
        for (int i = 0; i < 8; ++i) v += red[i][q];
        float inv = (e > s) ? 1.0f / (float)(e - s) : 1.0f;
        float p = v * inv;
        float p0 = p * WD[q * 2 + 0];
        float p1 = p * WD[q * 2 + 1];
        #pragma unroll
        for (int off = 16; off; off >>= 1) {
            p0 += __shfl_down(p0, off, 32);
            p1 += __shfl_down(p1, off, 32);
        }
        if (q == 0) {
            float l0 = p0 + BD[0], l1 = p1 + BD[1];
            float m = fmaxf(l0, l1);
            float e0 = expf(l0 - m), e1 = expf(l1 - m);
            float si = 1.0f / (e0 + e1);
            OUT[g * 2 + 0] = e0 * si;
            OUT[g * 2 + 1] = e1 * si;
        }
    }
}

extern "C" void kernel_launch(void* const* d_in, const int* in_sizes, int n_in,
                              void* d_out, int out_size, void* d_ws, size_t ws_size,
                              hipStream_t stream)
{
    const float* x    = (const float*)d_in[0];
    const float* ew   = (const float*)d_in[1];
    const int*   er   = (const int*)d_in[2];
    const int*   ec   = (const int*)d_in[3];
    const int*   seg  = (const int*)d_in[4];
    const float* w1_1 = (const float*)d_in[5];
    const float* w2_1 = (const float*)d_in[6];
    const float* b_1  = (const float*)d_in[7];
    const float* w1_2 = (const float*)d_in[8];
    const float* w2_2 = (const float*)d_in[9];
    const float* b_2  = (const float*)d_in[10];
    const float* w1_3 = (const float*)d_in[11];
    const float* w2_3 = (const float*)d_in[12];
    const float* b_3  = (const float*)d_in[13];
    const float* wd   = (const float*)d_in[14];
    const float* bd   = (const float*)d_in[15];

    float* ws = (float*)d_ws;
    int*   IW = (int*)d_ws;
    // Fully disjoint workspace — no aliasing hazards.
    __half* XPh    = (__half*)ws;                   // N x 32 fp16
    __half* CIa    = (__half*)(ws + 800000);        // N x 32 fp16
    unsigned int* tmp_sd = (unsigned int*)(ws + 1600000);  // E x 4B
    __half* tmp_w  = (__half*)(ws + 2400000);       // E x 2B
    __half* H2h    = (__half*)(ws + 3200000);       // N x 64 fp16
    __half* A2h    = (__half*)(ws + 4800000);       // N x 64 fp16
    __half* H3h    = (__half*)(ws + 6400000);       // N x 32 fp16
    __half* B2h    = (__half*)(ws + 7200000);       // N x 32 fp16
    unsigned int* packed = (unsigned int*)(IW + 8000000);  // E x 4B
    int*    rowptr = IW + 9000000;                  // N+1
    int*    ghist  = IW + 9060000;                  // NCB*256
    int*    bsum   = IW + 9115000;                  // NCB
    int*    start  = IW + 9120000;                  // G+1
    float*  WP     = ws + 9125000;                  // 64 x 128 packed layer-1 W

    dim3 blk(256);
    const int MB = (N_NODES + 63) / 64;             // 782

    // ---- CSR build + prep (4 dispatches; bsort fuses layer-1 aggx) ----
    hist_prep<<<dim3(256 + 6478), blk, 0, stream>>>(er, x, seg, w1_1, w2_1,
                                                    ghist, XPh, start, WP);
    scan1<<<dim3(NCB), blk, 0, stream>>>(ghist, bsum);
    c_scatter<<<dim3(256), blk, 0, stream>>>(er, ec, ew, ghist, bsum, tmp_sd, tmp_w);
    bsort_aggx<<<dim3(NCB), dim3(512), 0, stream>>>(tmp_sd, tmp_w, bsum, XPh,
                                                    packed, rowptr, CIa);

    // Layers 1+2 fused dense: [CIa|XPh] @ WP + b1 -> relu -> @[W1_2|W2_2]
    dense12_kernel<<<dim3(MB), dim3(512), 0, stream>>>(CIa, XPh, WP, b_1,
                                                       w1_2, w2_2, b_2, H2h, A2h);
    spmm_h<64><<<dim3((N_NODES + 31) / 32), blk, 0, stream>>>(H2h, rowptr, packed, A2h);
    // Layer 3: relu(h2h)(64) -> 32; both outputs fp16
    dense3_kernel<<<dim3(MB), blk, 0, stream>>>(A2h, w1_3, w2_3, b_3, H3h, B2h);
    spmm_h<32><<<dim3(MB), blk, 0, stream>>>(H3h, rowptr, packed, B2h);

    // Pool + head (fused, atomic-free)
    pool_kernel<<<dim3(N_GRAPHS), blk, 0, stream>>>(B2h, start, wd, bd, (float*)d_out);
}